// Round 15
// baseline (969.469 us; speedup 1.0000x reference)
//
#include <hip/hip_runtime.h>
#include <math.h>

// ---- constants from the reference ----
#define C_TP1_SS   0.125f          // 1/sqrt(64*1)
#define C_TP1_VV   0.1020620726f   // (1/sqrt(3))/sqrt(32*1)
#define C_TP1_SV   0.125f          // 1/sqrt(64*1)
#define C_TP1_VS   0.1767766953f   // 1/sqrt(32*1)
#define C_LIN_S    0.125f          // 1/sqrt(64)
#define C_LIN_V    0.1767766953f   // 1/sqrt(32)
#define C_TP2_SS   0.015625f       // 1/sqrt(64*64)
#define C_TP2_VV   0.0180421959f   // (1/sqrt(3))/32
#define C_TP2_SVVS 0.0220970869f   // 1/sqrt(2048)

typedef __attribute__((ext_vector_type(8))) short short8;
typedef __attribute__((ext_vector_type(16))) float f32x16;

__device__ __forceinline__ float sigmoidf_(float x) { return 1.f / (1.f + __expf(-x)); }

__device__ __forceinline__ unsigned short f2bf(float f) {
    unsigned int x = __float_as_uint(f);
    unsigned int r = x + 0x7FFFu + ((x >> 16) & 1u);
    return (unsigned short)(r >> 16);
}

__device__ __forceinline__ unsigned int pack2(float lo, float hi) {
    unsigned int r;
    asm("v_cvt_pk_bf16_f32 %0, %1, %2" : "=v"(r) : "v"(lo), "v"(hi));
    return r;
}

__device__ __forceinline__ float blo(unsigned int v) { return __uint_as_float(v << 16); }
__device__ __forceinline__ float bhi(unsigned int v) { return __uint_as_float(v & 0xffff0000u); }

__device__ __forceinline__ short8 as_s8(int4 v) { union { int4 a; short8 b; } u_; u_.a = v; return u_.b; }

__device__ __forceinline__ short8 pack8(float a0, float a1, float a2, float a3,
                                        float a4, float a5, float a6, float a7) {
    union { int i[4]; short8 s; } u_;
    asm("v_cvt_pk_bf16_f32 %0, %1, %2" : "=v"(u_.i[0]) : "v"(a0), "v"(a1));
    asm("v_cvt_pk_bf16_f32 %0, %1, %2" : "=v"(u_.i[1]) : "v"(a2), "v"(a3));
    asm("v_cvt_pk_bf16_f32 %0, %1, %2" : "=v"(u_.i[2]) : "v"(a4), "v"(a5));
    asm("v_cvt_pk_bf16_f32 %0, %1, %2" : "=v"(u_.i[3]) : "v"(a6), "v"(a7));
    return u_.s;
}

// bf16-staging loaders (element offset must be 4-aligned for ld4bf)
__device__ __forceinline__ float4 ld4bf(const unsigned short* p) {
    uint2 v = *(const uint2*)p;
    float4 r;
    r.x = __uint_as_float(v.x << 16);
    r.y = __uint_as_float(v.x & 0xffff0000u);
    r.z = __uint_as_float(v.y << 16);
    r.w = __uint_as_float(v.y & 0xffff0000u);
    return r;
}
__device__ __forceinline__ float ldbf(const unsigned short* p) {
    return __uint_as_float(((unsigned int)*p) << 16);
}

// ============ K_pre v3: tiled GEMM, outputs bf16 PREb with tp1 constants folded (VERIFIED) ============
__global__ __launch_bounds__(256, 2) void k_pre(const float* __restrict__ ns, const float* __restrict__ nv,
                                                const float* __restrict__ Wss, const float* __restrict__ Wvv,
                                                const float* __restrict__ Wsv, const float* __restrict__ Wvs,
                                                unsigned short* __restrict__ PREb, int N)
{
    __shared__ float smem[17728];
    float* sWss = smem;            // 6144
    float* sWvv = smem + 6144;     // 3072
    float* sWsv = smem + 9216;     // 2048
    float* sWvs = smem + 11264;    // 1024
    float* nsT  = smem + 12288;    // 64*34
    float* nvT  = smem + 14464;    // 96*34
    int tid = threadIdx.x;
    int base = blockIdx.x * 32;

    for (int i = tid; i < 6144; i += 256) sWss[i] = Wss[i];
    for (int i = tid; i < 3072; i += 256) sWvv[i] = Wvv[i];
    for (int i = tid; i < 2048; i += 256) sWsv[i] = Wsv[i];
    for (int i = tid; i < 1024; i += 256) sWvs[i] = Wvs[i];
    for (int i = tid; i < 2048; i += 256) {
        int m = i >> 6, u = i & 63;
        int n = base + m;
        nsT[u * 34 + m] = (n < N) ? ns[(size_t)n * 64 + u] : 0.f;
    }
    for (int i = tid; i < 3072; i += 256) {
        int m = i / 96, f = i % 96;
        int u = f / 3, c = f % 3;
        int n = base + m;
        nvT[(c * 32 + u) * 34 + m] = (n < N) ? nv[(size_t)n * 96 + f] : 0.f;
    }
    __syncthreads();

    int tx = tid & 15, ty = tid >> 4;
    int m2 = tx * 2;
    int e6 = ty * 6, e2 = ty * 2;

    float pP[2][6] = {};
    float pQ[2][6][3] = {};
    float pS[2][2] = {};
    float pV[2][2][3] = {};

    for (int u = 0; u < 64; ++u) {
        float2 x = *(const float2*)&nsT[u * 34 + m2];
        float w6[6];
        *(float2*)&w6[0] = *(const float2*)&sWss[u * 96 + e6 + 0];
        *(float2*)&w6[2] = *(const float2*)&sWss[u * 96 + e6 + 2];
        *(float2*)&w6[4] = *(const float2*)&sWss[u * 96 + e6 + 4];
        float2 w2 = *(const float2*)&sWsv[u * 32 + e2];
#pragma unroll
        for (int j = 0; j < 6; ++j) { pP[0][j] += x.x * w6[j]; pP[1][j] += x.y * w6[j]; }
        pS[0][0] += x.x * w2.x; pS[0][1] += x.x * w2.y;
        pS[1][0] += x.y * w2.x; pS[1][1] += x.y * w2.y;
    }
    for (int u = 0; u < 32; ++u) {
        float2 x0 = *(const float2*)&nvT[(0 * 32 + u) * 34 + m2];
        float2 x1 = *(const float2*)&nvT[(1 * 32 + u) * 34 + m2];
        float2 x2 = *(const float2*)&nvT[(2 * 32 + u) * 34 + m2];
        float w6[6];
        *(float2*)&w6[0] = *(const float2*)&sWvv[u * 96 + e6 + 0];
        *(float2*)&w6[2] = *(const float2*)&sWvv[u * 96 + e6 + 2];
        *(float2*)&w6[4] = *(const float2*)&sWvv[u * 96 + e6 + 4];
        float2 w2 = *(const float2*)&sWvs[u * 32 + e2];
#pragma unroll
        for (int j = 0; j < 6; ++j) {
            pQ[0][j][0] += x0.x * w6[j]; pQ[1][j][0] += x0.y * w6[j];
            pQ[0][j][1] += x1.x * w6[j]; pQ[1][j][1] += x1.y * w6[j];
            pQ[0][j][2] += x2.x * w6[j]; pQ[1][j][2] += x2.y * w6[j];
        }
        pV[0][0][0] += x0.x * w2.x; pV[0][1][0] += x0.x * w2.y;
        pV[1][0][0] += x0.y * w2.x; pV[1][1][0] += x0.y * w2.y;
        pV[0][0][1] += x1.x * w2.x; pV[0][1][1] += x1.x * w2.y;
        pV[1][0][1] += x1.y * w2.x; pV[1][1][1] += x1.y * w2.y;
        pV[0][0][2] += x2.x * w2.x; pV[0][1][2] += x2.x * w2.y;
        pV[1][0][2] += x2.y * w2.x; pV[1][1][2] += x2.y * w2.y;
    }

    __syncthreads();
    unsigned short* PT = (unsigned short*)smem;   // [32][512] ushort
#pragma unroll
    for (int m = 0; m < 2; ++m) {
        int nr = m2 + m;
#pragma unroll
        for (int j = 0; j < 6; ++j) {
            int e = e6 + j;
            unsigned int lo = pack2(C_TP1_SS * pP[m][j], C_TP1_VV * pQ[m][j][0]);
            unsigned int hi = pack2(C_TP1_VV * pQ[m][j][1], C_TP1_VV * pQ[m][j][2]);
            *(uint2*)&PT[nr * 512 + e * 4] = make_uint2(lo, hi);
        }
#pragma unroll
        for (int j = 0; j < 2; ++j) {
            int w = e2 + j;
            unsigned int lo = pack2(C_TP1_SV * pS[m][j], C_TP1_VS * pV[m][j][0]);
            unsigned int hi = pack2(C_TP1_VS * pV[m][j][1], C_TP1_VS * pV[m][j][2]);
            *(uint2*)&PT[nr * 512 + (96 + w) * 4] = make_uint2(lo, hi);
        }
    }
    __syncthreads();
    for (int i = tid; i < 2048; i += 256) {
        int n = base + (i >> 6);
        if (n < N) ((int4*)PREb)[(size_t)base * 64 + i] = ((const int4*)PT)[i];
    }
}

// ============ CSR build: histogram -> scan -> scatter (VERIFIED) ============
__global__ void k_hist(const int* __restrict__ erow, int* __restrict__ CNT, int E)
{
    int e = blockIdx.x * 256 + threadIdx.x;
    if (e < E) atomicAdd(&CNT[erow[e]], 1);
}

__global__ void k_scan(const int* __restrict__ CNT, int* __restrict__ OFFS, int N, int E)
{
    __shared__ int part[1024];
    int t = threadIdx.x;
    int chunk = (N + 1023) >> 10;
    int b0 = t * chunk; if (b0 > N) b0 = N;
    int b1 = b0 + chunk; if (b1 > N) b1 = N;
    int s = 0;
    for (int i = b0; i < b1; ++i) s += CNT[i];
    part[t] = s;
    __syncthreads();
    for (int off = 1; off < 1024; off <<= 1) {
        int v = (t >= off) ? part[t - off] : 0;
        __syncthreads();
        part[t] += v;
        __syncthreads();
    }
    int run = part[t] - s;
    for (int i = b0; i < b1; ++i) { OFFS[i] = run; run += CNT[i]; }
    if (t == 1023) OFFS[N] = E;
}

__global__ void k_scatter(const int* __restrict__ erow, const int* __restrict__ ecol,
                          const float4* __restrict__ esh, const int* __restrict__ OFFS,
                          int* __restrict__ CUR, int* __restrict__ EJ,
                          float4* __restrict__ ESHS, int E)
{
    int e = blockIdx.x * 256 + threadIdx.x;
    if (e >= E) return;
    int r = erow[e];
    int p = OFFS[r] + atomicAdd(&CUR[r], 1);
    EJ[p] = ecol[e];
    ESHS[p] = esh[e];
}

// ============ K_agg: one wave per node; gather bf16 PRE rows; register accumulate (VERIFIED) ============
__global__ void k_agg(const unsigned short* __restrict__ PREb, const int* __restrict__ EJ,
                      const float4* __restrict__ ESHS, const int* __restrict__ OFFS,
                      float* __restrict__ AGG, int N)
{
    int wv = blockIdx.x * 4 + (threadIdx.x >> 6);
    if (wv >= N) return;
    int lane = threadIdx.x & 63;
    int beg = OFFS[wv], end = OFFS[wv + 1];
    const int4* pb = (const int4*)PREb;
    float a0 = 0.f, a1 = 0.f;
    float b00 = 0.f, b01 = 0.f, b02 = 0.f, b10 = 0.f, b11 = 0.f, b12 = 0.f;
    int gsrc = (lane >= 48) ? (lane - 16) : lane;
    for (int i = beg; i < end; ++i) {
        int j = EJ[i];
        float4 sh = ESHS[i];
        int4 g = pb[(size_t)j * 64 + lane];
        unsigned int gx = (unsigned int)g.x, gy = (unsigned int)g.y;
        unsigned int gz = (unsigned int)g.z, gw = (unsigned int)g.w;
        float P0 = blo(gx), Q00 = bhi(gx), Q01 = blo(gy), Q02 = bhi(gy);
        float P1 = blo(gz), Q10 = bhi(gz), Q11 = blo(gw), Q12 = bhi(gw);
        float ms0 = sh.x * P0 + sh.y * Q00 + sh.z * Q01 + sh.w * Q02;
        float ms1 = sh.x * P1 + sh.y * Q10 + sh.z * Q11 + sh.w * Q12;
        float sg0 = sigmoidf_(ms0);
        float sg1 = sigmoidf_(ms1);
        float sw0 = __shfl(sg0, gsrc);
        float sw1 = __shfl(sg1, gsrc);
        if (lane < 32) {
            a0 += ms0 * sg0;
            a1 += ms1 * sg1;
        } else if (lane >= 48) {
            b00 += (sh.y * P0 + sh.x * Q00) * sw0;
            b01 += (sh.z * P0 + sh.x * Q01) * sw0;
            b02 += (sh.w * P0 + sh.x * Q02) * sw0;
            b10 += (sh.y * P1 + sh.x * Q10) * sw1;
            b11 += (sh.z * P1 + sh.x * Q11) * sw1;
            b12 += (sh.w * P1 + sh.x * Q12) * sw1;
        }
    }
    float* ab = AGG + (size_t)wv * 160;
    if (lane < 32) {
        *(float2*)&ab[2 * lane] = make_float2(a0, a1);
    } else if (lane >= 48) {
        int o = 64 + 6 * (lane - 48);
        *(float2*)&ab[o + 0] = make_float2(b00, b01);
        *(float2*)&ab[o + 2] = make_float2(b02, b10);
        *(float2*)&ab[o + 4] = make_float2(b11, b12);
    }
}

// ============ K_lin1: apply lin1 to aggregates, in place (VERIFIED) ============
__global__ void k_lin1(float* __restrict__ AGG, const float* __restrict__ L1s,
                       const float* __restrict__ L1v, int N)
{
    __shared__ float sLs[64 * 64];
    __shared__ float sLv[32 * 32];
    __shared__ float sS[4][64];
    __shared__ float sV[4][96];
    int tid = threadIdx.x;
    for (int i = tid; i < 64 * 64; i += 256) sLs[i] = L1s[i];
    for (int i = tid; i < 32 * 32; i += 256) sLv[i] = L1v[i];
    __syncthreads();
    int wid = tid >> 6, lane = tid & 63;
    int gw = blockIdx.x * 4 + wid, nw = gridDim.x * 4;
    for (int n = gw; n < N; n += nw) {
        float* base = AGG + (size_t)n * 160;
        sS[wid][lane] = base[lane];
        sV[wid][lane] = base[64 + lane];
        if (lane < 32) sV[wid][64 + lane] = base[128 + lane];
        float acc = 0.f;
        for (int u = 0; u < 64; ++u) acc += sS[wid][u] * sLs[u * 64 + lane];
        float o0 = 0.f, o1 = 0.f, o2 = 0.f;
        if (lane < 32) {
            for (int u = 0; u < 32; ++u) {
                float wv = sLv[u * 32 + lane];
                o0 += sV[wid][u * 3 + 0] * wv;
                o1 += sV[wid][u * 3 + 1] * wv;
                o2 += sV[wid][u * 3 + 2] * wv;
            }
        }
        base[lane] = C_LIN_S * acc;
        if (lane < 32) {
            base[64 + lane * 3 + 0] = C_LIN_V * o0;
            base[64 + lane * 3 + 1] = C_LIN_V * o1;
            base[64 + lane * 3 + 2] = C_LIN_V * o2;
        }
    }
}

// ============ K_wprep v4: ALL regions in swizzled per-lane fragment order (VERIFIED r14) ============
__global__ void k_wprep(const float* __restrict__ W2ss, const float* __restrict__ W2vv,
                        const float* __restrict__ W2sv, const float* __restrict__ W2vs,
                        unsigned short* __restrict__ WT)
{
    int i = blockIdx.x * 256 + threadIdx.x;
    if (i >= 819200) return;
    float val;
    if (i < 393216) {
        int nt = i / 131072;
        int r  = i % 131072;
        int kb = r >> 9;
        int q  = r & 511;
        int lane = q >> 3, j = q & 7;
        int w = nt * 32 + (lane & 31);
        int k = kb * 16 + (lane >> 5) * 8 + j;
        val = W2ss[(size_t)k * 96 + w] * C_TP2_SS;
    } else if (i < 688128) {
        int ii = i - 393216;
        int nt = ii / 98304;
        int r  = ii % 98304;
        int kb = r >> 9;
        int q  = r & 511;
        int lane = q >> 3, j = q & 7;
        int w = nt * 32 + (lane & 31);
        int k = kb * 16 + (lane >> 5) * 8 + j;
        int q2 = k & 1023;
        val = W2vv[(size_t)q2 * 96 + w] * C_TP2_VV;
    } else if (i < 753664) {
        int ii = i - 688128;
        int kb = ii >> 9;
        int q  = ii & 511;
        int lane = q >> 3, j = q & 7;
        int w = lane & 31;
        int k = kb * 16 + (lane >> 5) * 8 + j;
        val = W2sv[(size_t)k * 32 + w] * C_TP2_SVVS;
    } else {
        int ii = i - 753664;
        int kb = ii >> 9;
        int q  = ii & 511;
        int lane = q >> 3, j = q & 7;
        int w = lane & 31;
        int k = kb * 16 + (lane >> 5) * 8 + j;
        val = W2vs[(size_t)k * 32 + w] * C_TP2_SVVS;
    }
    WT[i] = f2bf(val);
}

// ============ K4ab_mfma v10: r14 VERIFIED structure; node staging in bf16 -> 24.6KB LDS, 5 blocks/CU ============
// ONLY change vs verified r14: staging arrays are bf16 (ushort) overlaid on the epilogue
// float buffer; reads unpack via ld4bf/ldbf. Same layout/strides/loop structure/B addressing.
#define OFF_NS 0
#define OFF_AS 2176
#define OFF_NV 4352
#define OFF_AV 7552
__global__ __launch_bounds__(256, 5) void k4ab_mfma(const float* __restrict__ ns, const float* __restrict__ nv,
                                                    const float* __restrict__ AGG,
                                                    const unsigned short* __restrict__ WT,
                                                    float* __restrict__ SOUT, float* __restrict__ VOUT, int N)
{
    __shared__ float smem[6144];            // 24.6 KB: staging (bf16 overlay) then epilogue
    unsigned short* stg = (unsigned short*)smem;
    const unsigned short* Wt_ss = WT;
    const unsigned short* Wt_vv = WT + 393216;
    const unsigned short* Wt_sv = WT + 688128;
    const unsigned short* Wt_vs = WT + 753664;

    int tid = threadIdx.x;
    int base = blockIdx.x * 32;

    for (int i = tid; i < 2048; i += 256) {
        int mm = i >> 6, u = i & 63;
        int n = base + mm;
        stg[OFF_NS + mm * 68 + u] = f2bf((n < N) ? ns[(size_t)n * 64 + u] : 0.f);
        stg[OFF_AS + mm * 68 + u] = f2bf((n < N) ? AGG[(size_t)n * 160 + u] : 0.f);
    }
    for (int i = tid; i < 3072; i += 256) {
        int mm = i / 96, r = i % 96;
        int c = r >> 5, q = r & 31;
        int n = base + mm;
        stg[OFF_NV + mm * 100 + r] = f2bf((n < N) ? nv[(size_t)n * 96 + q * 3 + c] : 0.f);
        stg[OFF_AV + mm * 100 + r] = f2bf((n < N) ? AGG[(size_t)n * 160 + 64 + q * 3 + c] : 0.f);
    }
    __syncthreads();

    int wid = tid >> 6;
    int l = tid & 63;
    int m = l & 31;
    int half = l >> 5;
    const unsigned short* pns = stg + OFF_NS + m * 68;
    const unsigned short* pas = stg + OFF_AS + m * 68;
    const unsigned short* pnv = stg + OFF_NV + m * 100;
    const unsigned short* pav = stg + OFF_AV + m * 100;

    f32x16 accA[3];
    f32x16 accP[3];
#pragma unroll
    for (int a = 0; a < 3; ++a) {
#pragma unroll
        for (int r = 0; r < 16; ++r) { accA[a][r] = 0.f; accP[a][r] = 0.f; }
    }

    if (wid == 0) {
        // ---- ss: K=4096.  y in regs; af shared across 3 nt; swizzled coalesced B ----
        float4 ys[4][2];
#pragma unroll
        for (int t = 0; t < 4; ++t) {
            ys[t][0] = ld4bf(&pas[t * 16 + half * 8]);
            ys[t][1] = ld4bf(&pas[t * 16 + half * 8 + 4]);
        }
        const int4* wb = (const int4*)Wt_ss + l;
        for (int u0 = 0; u0 < 64; u0 += 4) {
            float4 x4 = ld4bf(&pns[u0]);
#pragma unroll
            for (int uu = 0; uu < 4; ++uu) {
                float x = (uu == 0) ? x4.x : (uu == 1) ? x4.y : (uu == 2) ? x4.z : x4.w;
                const int4* wu = wb + (u0 + uu) * 256;
                int4 b[4];
#pragma unroll
                for (int t = 0; t < 4; ++t) b[t] = wu[t * 64];
                short8 af[4];
#pragma unroll
                for (int t = 0; t < 4; ++t)
                    af[t] = pack8(x * ys[t][0].x, x * ys[t][0].y, x * ys[t][0].z, x * ys[t][0].w,
                                  x * ys[t][1].x, x * ys[t][1].y, x * ys[t][1].z, x * ys[t][1].w);
#pragma unroll
                for (int nt = 0; nt < 3; ++nt) {
                    int4 nb[4];
                    if (nt < 2) {
#pragma unroll
                        for (int t = 0; t < 4; ++t) nb[t] = wu[(nt + 1) * 16384 + t * 64];
                    }
#pragma unroll
                    for (int t = 0; t < 4; ++t)
                        accA[nt] = __builtin_amdgcn_mfma_f32_32x32x16_bf16(af[t], as_s8(b[t]), accA[nt], 0, 0, 0);
                    if (nt < 2) {
#pragma unroll
                        for (int t = 0; t < 4; ++t) b[t] = nb[t];
                    }
                }
            }
        }
    } else if (wid == 1) {
        // ---- vv: K=3072.  y in regs; af shared across nt; swizzled coalesced B ----
        float4 yv[3][2][2];
#pragma unroll
        for (int c = 0; c < 3; ++c)
#pragma unroll
            for (int t = 0; t < 2; ++t) {
                yv[c][t][0] = ld4bf(&pav[c * 32 + t * 16 + half * 8]);
                yv[c][t][1] = ld4bf(&pav[c * 32 + t * 16 + half * 8 + 4]);
            }
        const int4* wb = (const int4*)Wt_vv + l;
#pragma unroll
        for (int c = 0; c < 3; ++c) {
            for (int u0 = 0; u0 < 32; u0 += 4) {
                float4 x4 = ld4bf(&pnv[c * 32 + u0]);
#pragma unroll
                for (int uu = 0; uu < 4; ++uu) {
                    float x = (uu == 0) ? x4.x : (uu == 1) ? x4.y : (uu == 2) ? x4.z : x4.w;
                    const int4* wu = wb + c * 4096 + (u0 + uu) * 128;
                    int4 b[2];
                    b[0] = wu[0];
                    b[1] = wu[64];
                    short8 af[2];
#pragma unroll
                    for (int t = 0; t < 2; ++t)
                        af[t] = pack8(x * yv[c][t][0].x, x * yv[c][t][0].y, x * yv[c][t][0].z, x * yv[c][t][0].w,
                                      x * yv[c][t][1].x, x * yv[c][t][1].y, x * yv[c][t][1].z, x * yv[c][t][1].w);
#pragma unroll
                    for (int nt = 0; nt < 3; ++nt) {
                        int4 nb[2];
                        if (nt < 2) {
                            nb[0] = wu[(nt + 1) * 12288];
                            nb[1] = wu[(nt + 1) * 12288 + 64];
                        }
                        accA[nt] = __builtin_amdgcn_mfma_f32_32x32x16_bf16(af[0], as_s8(b[0]), accA[nt], 0, 0, 0);
                        accA[nt] = __builtin_amdgcn_mfma_f32_32x32x16_bf16(af[1], as_s8(b[1]), accA[nt], 0, 0, 0);
                        if (nt < 2) { b[0] = nb[0]; b[1] = nb[1]; }
                    }
                }
            }
        }
    } else if (wid == 2) {
        // ---- sv: per c, K=2048, kb=u*2+t ----  (swizzled coalesced B, depth-2 pipeline)
        float4 yv[3][2][2];
#pragma unroll
        for (int c = 0; c < 3; ++c)
#pragma unroll
            for (int t = 0; t < 2; ++t) {
                yv[c][t][0] = ld4bf(&pav[c * 32 + t * 16 + half * 8]);
                yv[c][t][1] = ld4bf(&pav[c * 32 + t * 16 + half * 8 + 4]);
            }
        const int4* bp = (const int4*)Wt_sv + l;
#pragma unroll
        for (int c = 0; c < 3; ++c) {
            f32x16 acc;
#pragma unroll
            for (int r = 0; r < 16; ++r) acc[r] = 0.f;
            int4 b0 = bp[0], b1 = bp[64];
            int4 n0 = bp[128], n1 = bp[192];
            for (int u = 0; u < 64; ++u) {
                int up = (u + 2 < 64) ? (u + 2) : 63;
                const int4* bq = bp + up * 128;
                int4 p0 = bq[0], p1 = bq[64];
                float x = ldbf(&pns[u]);
#pragma unroll
                for (int t = 0; t < 2; ++t) {
                    short8 af = pack8(x * yv[c][t][0].x, x * yv[c][t][0].y, x * yv[c][t][0].z, x * yv[c][t][0].w,
                                      x * yv[c][t][1].x, x * yv[c][t][1].y, x * yv[c][t][1].z, x * yv[c][t][1].w);
                    int4 braw = (t == 0) ? b0 : b1;
                    acc = __builtin_amdgcn_mfma_f32_32x32x16_bf16(af, as_s8(braw), acc, 0, 0, 0);
                }
                b0 = n0; b1 = n1;
                n0 = p0; n1 = p1;
            }
            accP[c] = acc;
        }
    } else {
        // ---- vs: per c, K=2048, kb=u*4+t ----  (swizzled coalesced B, depth-2 pipeline)
        float4 ys[4][2];
#pragma unroll
        for (int t = 0; t < 4; ++t) {
            ys[t][0] = ld4bf(&pas[t * 16 + half * 8]);
            ys[t][1] = ld4bf(&pas[t * 16 + half * 8 + 4]);
        }
        const int4* bp = (const int4*)Wt_vs + l;
#pragma unroll
        for (int c = 0; c < 3; ++c) {
            f32x16 acc;
#pragma unroll
            for (int r = 0; r < 16; ++r) acc[r] = 0.f;
            int4 b0 = bp[0], b1 = bp[64], b2 = bp[128], b3 = bp[192];
            int4 n0 = bp[256], n1 = bp[320], n2 = bp[384], n3 = bp[448];
            for (int u = 0; u < 32; ++u) {
                int up = (u + 2 < 32) ? (u + 2) : 31;
                const int4* bq = bp + up * 256;
                int4 p0 = bq[0], p1 = bq[64], p2 = bq[128], p3 = bq[192];
                float x = ldbf(&pnv[c * 32 + u]);
#pragma unroll
                for (int t = 0; t < 4; ++t) {
                    short8 af = pack8(x * ys[t][0].x, x * ys[t][0].y, x * ys[t][0].z, x * ys[t][0].w,
                                      x * ys[t][1].x, x * ys[t][1].y, x * ys[t][1].z, x * ys[t][1].w);
                    int4 braw = (t == 0) ? b0 : (t == 1) ? b1 : (t == 2) ? b2 : b3;
                    acc = __builtin_amdgcn_mfma_f32_32x32x16_bf16(af, as_s8(braw), acc, 0, 0, 0);
                }
                b0 = n0; b1 = n1; b2 = n2; b3 = n3;
                n0 = p0; n1 = p1; n2 = p2; n3 = p3;
            }
            accP[c] = acc;
        }
    }

    __syncthreads();
    if (wid == 0) {
#pragma unroll
        for (int nt = 0; nt < 3; ++nt)
#pragma unroll
            for (int r = 0; r < 16; ++r) {
                int row = (r & 3) + 8 * (r >> 2) + 4 * half;
                smem[row * 96 + nt * 32 + m] = accA[nt][r];
            }
    }
    if (wid == 2) {
#pragma unroll
        for (int c = 0; c < 3; ++c)
#pragma unroll
            for (int r = 0; r < 16; ++r) {
                int row = (r & 3) + 8 * (r >> 2) + 4 * half;
                smem[3072 + row * 96 + m * 3 + c] = accP[c][r];
            }
    }
    __syncthreads();
    if (wid == 1) {
#pragma unroll
        for (int nt = 0; nt < 3; ++nt)
#pragma unroll
            for (int r = 0; r < 16; ++r) {
                int row = (r & 3) + 8 * (r >> 2) + 4 * half;
                smem[row * 96 + nt * 32 + m] += accA[nt][r];
            }
    }
    if (wid == 3) {
#pragma unroll
        for (int c = 0; c < 3; ++c)
#pragma unroll
            for (int r = 0; r < 16; ++r) {
                int row = (r & 3) + 8 * (r >> 2) + 4 * half;
                smem[3072 + row * 96 + m * 3 + c] += accP[c][r];
            }
    }
    __syncthreads();
    for (int i = tid; i < 3072; i += 256) {
        int n = base + i / 96;
        if (n < N) SOUT[(size_t)n * 96 + i % 96] = smem[i];
    }
    for (int i = tid; i < 3072; i += 256) {
        int n = base + i / 96;
        if (n < N) VOUT[(size_t)n * 96 + i % 96] = smem[3072 + i];
    }
}

// ============ K5: gate + lin2 + residual (VERIFIED) ============
__global__ void k5(const float* __restrict__ SOUT, const float* __restrict__ VOUT,
                   const float* __restrict__ ns, const float* __restrict__ nv,
                   const float* __restrict__ L2s, const float* __restrict__ L2v,
                   float* __restrict__ out, int N)
{
    __shared__ float sLs[64 * 64];
    __shared__ float sLv[32 * 32];
    __shared__ float sGS[4][64];
    __shared__ float sGV[4][96];
    int tid = threadIdx.x;
    for (int i = tid; i < 64 * 64; i += 256) sLs[i] = L2s[i];
    for (int i = tid; i < 32 * 32; i += 256) sLv[i] = L2v[i];
    __syncthreads();
    int wid = tid >> 6, lane = tid & 63;
    int gw = blockIdx.x * 4 + wid, nw = gridDim.x * 4;
    for (int n = gw; n < N; n += nw) {
        float so = SOUT[(size_t)n * 96 + lane];
        float sig = 0.f;
        if (lane < 32) sig = sigmoidf_(SOUT[(size_t)n * 96 + 64 + lane]);
        float sigA = __shfl(sig, lane / 3);
        float sigB = __shfl(sig, (64 + lane) / 3);
        sGS[wid][lane] = so * sigmoidf_(so);
        float v0 = VOUT[(size_t)n * 96 + lane];
        sGV[wid][lane] = v0 * sigA;
        if (lane < 32) {
            float v1 = VOUT[(size_t)n * 96 + 64 + lane];
            sGV[wid][64 + lane] = v1 * sigB;
        }
        float acc = 0.f;
        for (int u = 0; u < 64; ++u) acc += sGS[wid][u] * sLs[u * 64 + lane];
        out[(size_t)n * 64 + lane] = ns[(size_t)n * 64 + lane] + C_LIN_S * acc;
        if (lane < 32) {
            float a0 = 0.f, a1 = 0.f, a2 = 0.f;
            for (int u = 0; u < 32; ++u) {
                float wv = sLv[u * 32 + lane];
                a0 += sGV[wid][u * 3 + 0] * wv;
                a1 += sGV[wid][u * 3 + 1] * wv;
                a2 += sGV[wid][u * 3 + 2] * wv;
            }
            size_t ob = (size_t)N * 64 + (size_t)n * 96 + lane * 3;
            out[ob + 0] = nv[(size_t)n * 96 + lane * 3 + 0] + C_LIN_V * a0;
            out[ob + 1] = nv[(size_t)n * 96 + lane * 3 + 1] + C_LIN_V * a1;
            out[ob + 2] = nv[(size_t)n * 96 + lane * 3 + 2] + C_LIN_V * a2;
        }
    }
}

extern "C" void kernel_launch(void* const* d_in, const int* in_sizes, int n_in,
                              void* d_out, int out_size, void* d_ws, size_t ws_size,
                              hipStream_t stream)
{
    const float* node_s = (const float*)d_in[0];
    const float* node_v = (const float*)d_in[1];
    const float4* esh   = (const float4*)d_in[2];
    const int* erow     = (const int*)d_in[4];
    const int* ecol     = (const int*)d_in[5];
    const float* W1ss   = (const float*)d_in[6];
    const float* W1vv   = (const float*)d_in[7];
    const float* W1sv   = (const float*)d_in[8];
    const float* W1vs   = (const float*)d_in[9];
    const float* L1s    = (const float*)d_in[10];
    const float* L1v    = (const float*)d_in[11];
    const float* W2ss   = (const float*)d_in[12];
    const float* W2vv   = (const float*)d_in[13];
    const float* W2sv   = (const float*)d_in[14];
    const float* W2vs   = (const float*)d_in[15];
    const float* L2s    = (const float*)d_in[16];
    const float* L2v    = (const float*)d_in[17];
    int N = in_sizes[0] / 64;
    int E = in_sizes[4];

    char* ws = (char*)d_ws;
    float* AGG            = (float*)ws;                                   // N*160 f32
    unsigned short* PREb  = (unsigned short*)(ws + (size_t)N * 640);      // N*512 bf16
    float* SOUT           = (float*)(ws + (size_t)N * 640);               // aliases PREb (dead then)
    float* VOUT           = (float*)(ws + (size_t)N * 640 + (size_t)N * 384);
    unsigned short* WT    = (unsigned short*)(ws + (size_t)N * 1664);     // 819200 bf16
    int* EJ               = (int*)(ws + (size_t)N * 1664 + 1638400);      // E int
    float4* ESHS          = (float4*)((char*)EJ + (size_t)E * 4);         // E float4
    int* CNT              = (int*)((char*)ESHS + (size_t)E * 16);         // N int
    int* OFFS             = CNT + N;                                      // N+16 int
    int* CUR              = OFFS + N + 16;                                // N int

    hipMemsetAsync(CNT, 0, (size_t)(3 * N + 16) * 4, stream);
    k_pre<<<(N + 31) / 32, 256, 0, stream>>>(node_s, node_v, W1ss, W1vv, W1sv, W1vs, PREb, N);
    k_hist<<<(E + 255) / 256, 256, 0, stream>>>(erow, CNT, E);
    k_scan<<<1, 1024, 0, stream>>>(CNT, OFFS, N, E);
    k_scatter<<<(E + 255) / 256, 256, 0, stream>>>(erow, ecol, esh, OFFS, CUR, EJ, ESHS, E);
    k_agg<<<(N + 3) / 4, 256, 0, stream>>>(PREb, EJ, ESHS, OFFS, AGG, N);
    k_lin1<<<1024, 256, 0, stream>>>(AGG, L1s, L1v, N);
    k_wprep<<<3200, 256, 0, stream>>>(W2ss, W2vv, W2sv, W2vs, WT);
    k4ab_mfma<<<(N + 31) / 32, 256, 0, stream>>>(node_s, node_v, AGG, WT, SOUT, VOUT, N);
    k5<<<1024, 256, 0, stream>>>(SOUT, VOUT, node_s, node_v, L2s, L2v, (float*)d_out, N);
}

// Round 16
// 730.954 us; speedup vs baseline: 1.3263x; 1.3263x over previous
//
#include <hip/hip_runtime.h>
#include <math.h>

// ---- constants from the reference ----
#define C_TP1_SS   0.125f          // 1/sqrt(64*1)
#define C_TP1_VV   0.1020620726f   // (1/sqrt(3))/sqrt(32*1)
#define C_TP1_SV   0.125f          // 1/sqrt(64*1)
#define C_TP1_VS   0.1767766953f   // 1/sqrt(32*1)
#define C_LIN_S    0.125f          // 1/sqrt(64)
#define C_LIN_V    0.1767766953f   // 1/sqrt(32)
#define C_TP2_SS   0.015625f       // 1/sqrt(64*64)
#define C_TP2_VV   0.0180421959f   // (1/sqrt(3))/32
#define C_TP2_SVVS 0.0220970869f   // 1/sqrt(2048)

typedef __attribute__((ext_vector_type(8))) short short8;
typedef __attribute__((ext_vector_type(16))) float f32x16;

__device__ __forceinline__ float sigmoidf_(float x) { return 1.f / (1.f + __expf(-x)); }

__device__ __forceinline__ unsigned short f2bf(float f) {
    unsigned int x = __float_as_uint(f);
    unsigned int r = x + 0x7FFFu + ((x >> 16) & 1u);
    return (unsigned short)(r >> 16);
}

__device__ __forceinline__ unsigned int pack2(float lo, float hi) {
    unsigned int r;
    asm("v_cvt_pk_bf16_f32 %0, %1, %2" : "=v"(r) : "v"(lo), "v"(hi));
    return r;
}

__device__ __forceinline__ float blo(unsigned int v) { return __uint_as_float(v << 16); }
__device__ __forceinline__ float bhi(unsigned int v) { return __uint_as_float(v & 0xffff0000u); }

__device__ __forceinline__ short8 as_s8(int4 v) { union { int4 a; short8 b; } u_; u_.a = v; return u_.b; }

__device__ __forceinline__ short8 pack8(float a0, float a1, float a2, float a3,
                                        float a4, float a5, float a6, float a7) {
    union { int i[4]; short8 s; } u_;
    asm("v_cvt_pk_bf16_f32 %0, %1, %2" : "=v"(u_.i[0]) : "v"(a0), "v"(a1));
    asm("v_cvt_pk_bf16_f32 %0, %1, %2" : "=v"(u_.i[1]) : "v"(a2), "v"(a3));
    asm("v_cvt_pk_bf16_f32 %0, %1, %2" : "=v"(u_.i[2]) : "v"(a4), "v"(a5));
    asm("v_cvt_pk_bf16_f32 %0, %1, %2" : "=v"(u_.i[3]) : "v"(a6), "v"(a7));
    return u_.s;
}

// bf16-staging loaders (element offset must be 4-aligned for ld4bf)
__device__ __forceinline__ float4 ld4bf(const unsigned short* p) {
    uint2 v = *(const uint2*)p;
    float4 r;
    r.x = __uint_as_float(v.x << 16);
    r.y = __uint_as_float(v.x & 0xffff0000u);
    r.z = __uint_as_float(v.y << 16);
    r.w = __uint_as_float(v.y & 0xffff0000u);
    return r;
}
__device__ __forceinline__ float ldbf(const unsigned short* p) {
    return __uint_as_float(((unsigned int)*p) << 16);
}

// ============ K_pre v3: tiled GEMM, outputs bf16 PREb with tp1 constants folded (VERIFIED) ============
__global__ __launch_bounds__(256, 2) void k_pre(const float* __restrict__ ns, const float* __restrict__ nv,
                                                const float* __restrict__ Wss, const float* __restrict__ Wvv,
                                                const float* __restrict__ Wsv, const float* __restrict__ Wvs,
                                                unsigned short* __restrict__ PREb, int N)
{
    __shared__ float smem[17728];
    float* sWss = smem;            // 6144
    float* sWvv = smem + 6144;     // 3072
    float* sWsv = smem + 9216;     // 2048
    float* sWvs = smem + 11264;    // 1024
    float* nsT  = smem + 12288;    // 64*34
    float* nvT  = smem + 14464;    // 96*34
    int tid = threadIdx.x;
    int base = blockIdx.x * 32;

    for (int i = tid; i < 6144; i += 256) sWss[i] = Wss[i];
    for (int i = tid; i < 3072; i += 256) sWvv[i] = Wvv[i];
    for (int i = tid; i < 2048; i += 256) sWsv[i] = Wsv[i];
    for (int i = tid; i < 1024; i += 256) sWvs[i] = Wvs[i];
    for (int i = tid; i < 2048; i += 256) {
        int m = i >> 6, u = i & 63;
        int n = base + m;
        nsT[u * 34 + m] = (n < N) ? ns[(size_t)n * 64 + u] : 0.f;
    }
    for (int i = tid; i < 3072; i += 256) {
        int m = i / 96, f = i % 96;
        int u = f / 3, c = f % 3;
        int n = base + m;
        nvT[(c * 32 + u) * 34 + m] = (n < N) ? nv[(size_t)n * 96 + f] : 0.f;
    }
    __syncthreads();

    int tx = tid & 15, ty = tid >> 4;
    int m2 = tx * 2;
    int e6 = ty * 6, e2 = ty * 2;

    float pP[2][6] = {};
    float pQ[2][6][3] = {};
    float pS[2][2] = {};
    float pV[2][2][3] = {};

    for (int u = 0; u < 64; ++u) {
        float2 x = *(const float2*)&nsT[u * 34 + m2];
        float w6[6];
        *(float2*)&w6[0] = *(const float2*)&sWss[u * 96 + e6 + 0];
        *(float2*)&w6[2] = *(const float2*)&sWss[u * 96 + e6 + 2];
        *(float2*)&w6[4] = *(const float2*)&sWss[u * 96 + e6 + 4];
        float2 w2 = *(const float2*)&sWsv[u * 32 + e2];
#pragma unroll
        for (int j = 0; j < 6; ++j) { pP[0][j] += x.x * w6[j]; pP[1][j] += x.y * w6[j]; }
        pS[0][0] += x.x * w2.x; pS[0][1] += x.x * w2.y;
        pS[1][0] += x.y * w2.x; pS[1][1] += x.y * w2.y;
    }
    for (int u = 0; u < 32; ++u) {
        float2 x0 = *(const float2*)&nvT[(0 * 32 + u) * 34 + m2];
        float2 x1 = *(const float2*)&nvT[(1 * 32 + u) * 34 + m2];
        float2 x2 = *(const float2*)&nvT[(2 * 32 + u) * 34 + m2];
        float w6[6];
        *(float2*)&w6[0] = *(const float2*)&sWvv[u * 96 + e6 + 0];
        *(float2*)&w6[2] = *(const float2*)&sWvv[u * 96 + e6 + 2];
        *(float2*)&w6[4] = *(const float2*)&sWvv[u * 96 + e6 + 4];
        float2 w2 = *(const float2*)&sWvs[u * 32 + e2];
#pragma unroll
        for (int j = 0; j < 6; ++j) {
            pQ[0][j][0] += x0.x * w6[j]; pQ[1][j][0] += x0.y * w6[j];
            pQ[0][j][1] += x1.x * w6[j]; pQ[1][j][1] += x1.y * w6[j];
            pQ[0][j][2] += x2.x * w6[j]; pQ[1][j][2] += x2.y * w6[j];
        }
        pV[0][0][0] += x0.x * w2.x; pV[0][1][0] += x0.x * w2.y;
        pV[1][0][0] += x0.y * w2.x; pV[1][1][0] += x0.y * w2.y;
        pV[0][0][1] += x1.x * w2.x; pV[0][1][1] += x1.x * w2.y;
        pV[1][0][1] += x1.y * w2.x; pV[1][1][1] += x1.y * w2.y;
        pV[0][0][2] += x2.x * w2.x; pV[0][1][2] += x2.x * w2.y;
        pV[1][0][2] += x2.y * w2.x; pV[1][1][2] += x2.y * w2.y;
    }

    __syncthreads();
    unsigned short* PT = (unsigned short*)smem;   // [32][512] ushort
#pragma unroll
    for (int m = 0; m < 2; ++m) {
        int nr = m2 + m;
#pragma unroll
        for (int j = 0; j < 6; ++j) {
            int e = e6 + j;
            unsigned int lo = pack2(C_TP1_SS * pP[m][j], C_TP1_VV * pQ[m][j][0]);
            unsigned int hi = pack2(C_TP1_VV * pQ[m][j][1], C_TP1_VV * pQ[m][j][2]);
            *(uint2*)&PT[nr * 512 + e * 4] = make_uint2(lo, hi);
        }
#pragma unroll
        for (int j = 0; j < 2; ++j) {
            int w = e2 + j;
            unsigned int lo = pack2(C_TP1_SV * pS[m][j], C_TP1_VS * pV[m][j][0]);
            unsigned int hi = pack2(C_TP1_VS * pV[m][j][1], C_TP1_VS * pV[m][j][2]);
            *(uint2*)&PT[nr * 512 + (96 + w) * 4] = make_uint2(lo, hi);
        }
    }
    __syncthreads();
    for (int i = tid; i < 2048; i += 256) {
        int n = base + (i >> 6);
        if (n < N) ((int4*)PREb)[(size_t)base * 64 + i] = ((const int4*)PT)[i];
    }
}

// ============ CSR build: histogram -> scan -> scatter (VERIFIED) ============
__global__ void k_hist(const int* __restrict__ erow, int* __restrict__ CNT, int E)
{
    int e = blockIdx.x * 256 + threadIdx.x;
    if (e < E) atomicAdd(&CNT[erow[e]], 1);
}

__global__ void k_scan(const int* __restrict__ CNT, int* __restrict__ OFFS, int N, int E)
{
    __shared__ int part[1024];
    int t = threadIdx.x;
    int chunk = (N + 1023) >> 10;
    int b0 = t * chunk; if (b0 > N) b0 = N;
    int b1 = b0 + chunk; if (b1 > N) b1 = N;
    int s = 0;
    for (int i = b0; i < b1; ++i) s += CNT[i];
    part[t] = s;
    __syncthreads();
    for (int off = 1; off < 1024; off <<= 1) {
        int v = (t >= off) ? part[t - off] : 0;
        __syncthreads();
        part[t] += v;
        __syncthreads();
    }
    int run = part[t] - s;
    for (int i = b0; i < b1; ++i) { OFFS[i] = run; run += CNT[i]; }
    if (t == 1023) OFFS[N] = E;
}

__global__ void k_scatter(const int* __restrict__ erow, const int* __restrict__ ecol,
                          const float4* __restrict__ esh, const int* __restrict__ OFFS,
                          int* __restrict__ CUR, int* __restrict__ EJ,
                          float4* __restrict__ ESHS, int E)
{
    int e = blockIdx.x * 256 + threadIdx.x;
    if (e >= E) return;
    int r = erow[e];
    int p = OFFS[r] + atomicAdd(&CUR[r], 1);
    EJ[p] = ecol[e];
    ESHS[p] = esh[e];
}

// ============ K_agg: one wave per node; gather bf16 PRE rows; register accumulate (VERIFIED) ============
__global__ void k_agg(const unsigned short* __restrict__ PREb, const int* __restrict__ EJ,
                      const float4* __restrict__ ESHS, const int* __restrict__ OFFS,
                      float* __restrict__ AGG, int N)
{
    int wv = blockIdx.x * 4 + (threadIdx.x >> 6);
    if (wv >= N) return;
    int lane = threadIdx.x & 63;
    int beg = OFFS[wv], end = OFFS[wv + 1];
    const int4* pb = (const int4*)PREb;
    float a0 = 0.f, a1 = 0.f;
    float b00 = 0.f, b01 = 0.f, b02 = 0.f, b10 = 0.f, b11 = 0.f, b12 = 0.f;
    int gsrc = (lane >= 48) ? (lane - 16) : lane;
    for (int i = beg; i < end; ++i) {
        int j = EJ[i];
        float4 sh = ESHS[i];
        int4 g = pb[(size_t)j * 64 + lane];
        unsigned int gx = (unsigned int)g.x, gy = (unsigned int)g.y;
        unsigned int gz = (unsigned int)g.z, gw = (unsigned int)g.w;
        float P0 = blo(gx), Q00 = bhi(gx), Q01 = blo(gy), Q02 = bhi(gy);
        float P1 = blo(gz), Q10 = bhi(gz), Q11 = blo(gw), Q12 = bhi(gw);
        float ms0 = sh.x * P0 + sh.y * Q00 + sh.z * Q01 + sh.w * Q02;
        float ms1 = sh.x * P1 + sh.y * Q10 + sh.z * Q11 + sh.w * Q12;
        float sg0 = sigmoidf_(ms0);
        float sg1 = sigmoidf_(ms1);
        float sw0 = __shfl(sg0, gsrc);
        float sw1 = __shfl(sg1, gsrc);
        if (lane < 32) {
            a0 += ms0 * sg0;
            a1 += ms1 * sg1;
        } else if (lane >= 48) {
            b00 += (sh.y * P0 + sh.x * Q00) * sw0;
            b01 += (sh.z * P0 + sh.x * Q01) * sw0;
            b02 += (sh.w * P0 + sh.x * Q02) * sw0;
            b10 += (sh.y * P1 + sh.x * Q10) * sw1;
            b11 += (sh.z * P1 + sh.x * Q11) * sw1;
            b12 += (sh.w * P1 + sh.x * Q12) * sw1;
        }
    }
    float* ab = AGG + (size_t)wv * 160;
    if (lane < 32) {
        *(float2*)&ab[2 * lane] = make_float2(a0, a1);
    } else if (lane >= 48) {
        int o = 64 + 6 * (lane - 48);
        *(float2*)&ab[o + 0] = make_float2(b00, b01);
        *(float2*)&ab[o + 2] = make_float2(b02, b10);
        *(float2*)&ab[o + 4] = make_float2(b11, b12);
    }
}

// ============ K_lin1: apply lin1 to aggregates, in place (VERIFIED) ============
__global__ void k_lin1(float* __restrict__ AGG, const float* __restrict__ L1s,
                       const float* __restrict__ L1v, int N)
{
    __shared__ float sLs[64 * 64];
    __shared__ float sLv[32 * 32];
    __shared__ float sS[4][64];
    __shared__ float sV[4][96];
    int tid = threadIdx.x;
    for (int i = tid; i < 64 * 64; i += 256) sLs[i] = L1s[i];
    for (int i = tid; i < 32 * 32; i += 256) sLv[i] = L1v[i];
    __syncthreads();
    int wid = tid >> 6, lane = tid & 63;
    int gw = blockIdx.x * 4 + wid, nw = gridDim.x * 4;
    for (int n = gw; n < N; n += nw) {
        float* base = AGG + (size_t)n * 160;
        sS[wid][lane] = base[lane];
        sV[wid][lane] = base[64 + lane];
        if (lane < 32) sV[wid][64 + lane] = base[128 + lane];
        float acc = 0.f;
        for (int u = 0; u < 64; ++u) acc += sS[wid][u] * sLs[u * 64 + lane];
        float o0 = 0.f, o1 = 0.f, o2 = 0.f;
        if (lane < 32) {
            for (int u = 0; u < 32; ++u) {
                float wv = sLv[u * 32 + lane];
                o0 += sV[wid][u * 3 + 0] * wv;
                o1 += sV[wid][u * 3 + 1] * wv;
                o2 += sV[wid][u * 3 + 2] * wv;
            }
        }
        base[lane] = C_LIN_S * acc;
        if (lane < 32) {
            base[64 + lane * 3 + 0] = C_LIN_V * o0;
            base[64 + lane * 3 + 1] = C_LIN_V * o1;
            base[64 + lane * 3 + 2] = C_LIN_V * o2;
        }
    }
}

// ============ K_wprep v4: ALL regions in swizzled per-lane fragment order (VERIFIED r14) ============
__global__ void k_wprep(const float* __restrict__ W2ss, const float* __restrict__ W2vv,
                        const float* __restrict__ W2sv, const float* __restrict__ W2vs,
                        unsigned short* __restrict__ WT)
{
    int i = blockIdx.x * 256 + threadIdx.x;
    if (i >= 819200) return;
    float val;
    if (i < 393216) {
        int nt = i / 131072;
        int r  = i % 131072;
        int kb = r >> 9;
        int q  = r & 511;
        int lane = q >> 3, j = q & 7;
        int w = nt * 32 + (lane & 31);
        int k = kb * 16 + (lane >> 5) * 8 + j;
        val = W2ss[(size_t)k * 96 + w] * C_TP2_SS;
    } else if (i < 688128) {
        int ii = i - 393216;
        int nt = ii / 98304;
        int r  = ii % 98304;
        int kb = r >> 9;
        int q  = r & 511;
        int lane = q >> 3, j = q & 7;
        int w = nt * 32 + (lane & 31);
        int k = kb * 16 + (lane >> 5) * 8 + j;
        int q2 = k & 1023;
        val = W2vv[(size_t)q2 * 96 + w] * C_TP2_VV;
    } else if (i < 753664) {
        int ii = i - 688128;
        int kb = ii >> 9;
        int q  = ii & 511;
        int lane = q >> 3, j = q & 7;
        int w = lane & 31;
        int k = kb * 16 + (lane >> 5) * 8 + j;
        val = W2sv[(size_t)k * 32 + w] * C_TP2_SVVS;
    } else {
        int ii = i - 753664;
        int kb = ii >> 9;
        int q  = ii & 511;
        int lane = q >> 3, j = q & 7;
        int w = lane & 31;
        int k = kb * 16 + (lane >> 5) * 8 + j;
        val = W2vs[(size_t)k * 32 + w] * C_TP2_SVVS;
    }
    WT[i] = f2bf(val);
}

// ============ K4ab_mfma v11: r15 body (VERIFIED numerics, absmax 0.469); launch_bounds(256,4) ============
// ONLY change vs r15: min-waves 5 -> 4 (VGPR cap 128, no accumulator spill; 4 blocks/CU).
#define OFF_NS 0
#define OFF_AS 2176
#define OFF_NV 4352
#define OFF_AV 7552
__global__ __launch_bounds__(256, 4) void k4ab_mfma(const float* __restrict__ ns, const float* __restrict__ nv,
                                                    const float* __restrict__ AGG,
                                                    const unsigned short* __restrict__ WT,
                                                    float* __restrict__ SOUT, float* __restrict__ VOUT, int N)
{
    __shared__ float smem[6144];            // 24.6 KB: staging (bf16 overlay) then epilogue
    unsigned short* stg = (unsigned short*)smem;
    const unsigned short* Wt_ss = WT;
    const unsigned short* Wt_vv = WT + 393216;
    const unsigned short* Wt_sv = WT + 688128;
    const unsigned short* Wt_vs = WT + 753664;

    int tid = threadIdx.x;
    int base = blockIdx.x * 32;

    for (int i = tid; i < 2048; i += 256) {
        int mm = i >> 6, u = i & 63;
        int n = base + mm;
        stg[OFF_NS + mm * 68 + u] = f2bf((n < N) ? ns[(size_t)n * 64 + u] : 0.f);
        stg[OFF_AS + mm * 68 + u] = f2bf((n < N) ? AGG[(size_t)n * 160 + u] : 0.f);
    }
    for (int i = tid; i < 3072; i += 256) {
        int mm = i / 96, r = i % 96;
        int c = r >> 5, q = r & 31;
        int n = base + mm;
        stg[OFF_NV + mm * 100 + r] = f2bf((n < N) ? nv[(size_t)n * 96 + q * 3 + c] : 0.f);
        stg[OFF_AV + mm * 100 + r] = f2bf((n < N) ? AGG[(size_t)n * 160 + 64 + q * 3 + c] : 0.f);
    }
    __syncthreads();

    int wid = tid >> 6;
    int l = tid & 63;
    int m = l & 31;
    int half = l >> 5;
    const unsigned short* pns = stg + OFF_NS + m * 68;
    const unsigned short* pas = stg + OFF_AS + m * 68;
    const unsigned short* pnv = stg + OFF_NV + m * 100;
    const unsigned short* pav = stg + OFF_AV + m * 100;

    f32x16 accA[3];
    f32x16 accP[3];
#pragma unroll
    for (int a = 0; a < 3; ++a) {
#pragma unroll
        for (int r = 0; r < 16; ++r) { accA[a][r] = 0.f; accP[a][r] = 0.f; }
    }

    if (wid == 0) {
        // ---- ss: K=4096.  y in regs; af shared across 3 nt; swizzled coalesced B ----
        float4 ys[4][2];
#pragma unroll
        for (int t = 0; t < 4; ++t) {
            ys[t][0] = ld4bf(&pas[t * 16 + half * 8]);
            ys[t][1] = ld4bf(&pas[t * 16 + half * 8 + 4]);
        }
        const int4* wb = (const int4*)Wt_ss + l;
        for (int u0 = 0; u0 < 64; u0 += 4) {
            float4 x4 = ld4bf(&pns[u0]);
#pragma unroll
            for (int uu = 0; uu < 4; ++uu) {
                float x = (uu == 0) ? x4.x : (uu == 1) ? x4.y : (uu == 2) ? x4.z : x4.w;
                const int4* wu = wb + (u0 + uu) * 256;
                int4 b[4];
#pragma unroll
                for (int t = 0; t < 4; ++t) b[t] = wu[t * 64];
                short8 af[4];
#pragma unroll
                for (int t = 0; t < 4; ++t)
                    af[t] = pack8(x * ys[t][0].x, x * ys[t][0].y, x * ys[t][0].z, x * ys[t][0].w,
                                  x * ys[t][1].x, x * ys[t][1].y, x * ys[t][1].z, x * ys[t][1].w);
#pragma unroll
                for (int nt = 0; nt < 3; ++nt) {
                    int4 nb[4];
                    if (nt < 2) {
#pragma unroll
                        for (int t = 0; t < 4; ++t) nb[t] = wu[(nt + 1) * 16384 + t * 64];
                    }
#pragma unroll
                    for (int t = 0; t < 4; ++t)
                        accA[nt] = __builtin_amdgcn_mfma_f32_32x32x16_bf16(af[t], as_s8(b[t]), accA[nt], 0, 0, 0);
                    if (nt < 2) {
#pragma unroll
                        for (int t = 0; t < 4; ++t) b[t] = nb[t];
                    }
                }
            }
        }
    } else if (wid == 1) {
        // ---- vv: K=3072.  y in regs; af shared across nt; swizzled coalesced B ----
        float4 yv[3][2][2];
#pragma unroll
        for (int c = 0; c < 3; ++c)
#pragma unroll
            for (int t = 0; t < 2; ++t) {
                yv[c][t][0] = ld4bf(&pav[c * 32 + t * 16 + half * 8]);
                yv[c][t][1] = ld4bf(&pav[c * 32 + t * 16 + half * 8 + 4]);
            }
        const int4* wb = (const int4*)Wt_vv + l;
#pragma unroll
        for (int c = 0; c < 3; ++c) {
            for (int u0 = 0; u0 < 32; u0 += 4) {
                float4 x4 = ld4bf(&pnv[c * 32 + u0]);
#pragma unroll
                for (int uu = 0; uu < 4; ++uu) {
                    float x = (uu == 0) ? x4.x : (uu == 1) ? x4.y : (uu == 2) ? x4.z : x4.w;
                    const int4* wu = wb + c * 4096 + (u0 + uu) * 128;
                    int4 b[2];
                    b[0] = wu[0];
                    b[1] = wu[64];
                    short8 af[2];
#pragma unroll
                    for (int t = 0; t < 2; ++t)
                        af[t] = pack8(x * yv[c][t][0].x, x * yv[c][t][0].y, x * yv[c][t][0].z, x * yv[c][t][0].w,
                                      x * yv[c][t][1].x, x * yv[c][t][1].y, x * yv[c][t][1].z, x * yv[c][t][1].w);
#pragma unroll
                    for (int nt = 0; nt < 3; ++nt) {
                        int4 nb[2];
                        if (nt < 2) {
                            nb[0] = wu[(nt + 1) * 12288];
                            nb[1] = wu[(nt + 1) * 12288 + 64];
                        }
                        accA[nt] = __builtin_amdgcn_mfma_f32_32x32x16_bf16(af[0], as_s8(b[0]), accA[nt], 0, 0, 0);
                        accA[nt] = __builtin_amdgcn_mfma_f32_32x32x16_bf16(af[1], as_s8(b[1]), accA[nt], 0, 0, 0);
                        if (nt < 2) { b[0] = nb[0]; b[1] = nb[1]; }
                    }
                }
            }
        }
    } else if (wid == 2) {
        // ---- sv: per c, K=2048, kb=u*2+t ----  (swizzled coalesced B, depth-2 pipeline)
        float4 yv[3][2][2];
#pragma unroll
        for (int c = 0; c < 3; ++c)
#pragma unroll
            for (int t = 0; t < 2; ++t) {
                yv[c][t][0] = ld4bf(&pav[c * 32 + t * 16 + half * 8]);
                yv[c][t][1] = ld4bf(&pav[c * 32 + t * 16 + half * 8 + 4]);
            }
        const int4* bp = (const int4*)Wt_sv + l;
#pragma unroll
        for (int c = 0; c < 3; ++c) {
            f32x16 acc;
#pragma unroll
            for (int r = 0; r < 16; ++r) acc[r] = 0.f;
            int4 b0 = bp[0], b1 = bp[64];
            int4 n0 = bp[128], n1 = bp[192];
            for (int u = 0; u < 64; ++u) {
                int up = (u + 2 < 64) ? (u + 2) : 63;
                const int4* bq = bp + up * 128;
                int4 p0 = bq[0], p1 = bq[64];
                float x = ldbf(&pns[u]);
#pragma unroll
                for (int t = 0; t < 2; ++t) {
                    short8 af = pack8(x * yv[c][t][0].x, x * yv[c][t][0].y, x * yv[c][t][0].z, x * yv[c][t][0].w,
                                      x * yv[c][t][1].x, x * yv[c][t][1].y, x * yv[c][t][1].z, x * yv[c][t][1].w);
                    int4 braw = (t == 0) ? b0 : b1;
                    acc = __builtin_amdgcn_mfma_f32_32x32x16_bf16(af, as_s8(braw), acc, 0, 0, 0);
                }
                b0 = n0; b1 = n1;
                n0 = p0; n1 = p1;
            }
            accP[c] = acc;
        }
    } else {
        // ---- vs: per c, K=2048, kb=u*4+t ----  (swizzled coalesced B, depth-2 pipeline)
        float4 ys[4][2];
#pragma unroll
        for (int t = 0; t < 4; ++t) {
            ys[t][0] = ld4bf(&pas[t * 16 + half * 8]);
            ys[t][1] = ld4bf(&pas[t * 16 + half * 8 + 4]);
        }
        const int4* bp = (const int4*)Wt_vs + l;
#pragma unroll
        for (int c = 0; c < 3; ++c) {
            f32x16 acc;
#pragma unroll
            for (int r = 0; r < 16; ++r) acc[r] = 0.f;
            int4 b0 = bp[0], b1 = bp[64], b2 = bp[128], b3 = bp[192];
            int4 n0 = bp[256], n1 = bp[320], n2 = bp[384], n3 = bp[448];
            for (int u = 0; u < 32; ++u) {
                int up = (u + 2 < 32) ? (u + 2) : 31;
                const int4* bq = bp + up * 256;
                int4 p0 = bq[0], p1 = bq[64], p2 = bq[128], p3 = bq[192];
                float x = ldbf(&pnv[c * 32 + u]);
#pragma unroll
                for (int t = 0; t < 4; ++t) {
                    short8 af = pack8(x * ys[t][0].x, x * ys[t][0].y, x * ys[t][0].z, x * ys[t][0].w,
                                      x * ys[t][1].x, x * ys[t][1].y, x * ys[t][1].z, x * ys[t][1].w);
                    int4 braw = (t == 0) ? b0 : (t == 1) ? b1 : (t == 2) ? b2 : b3;
                    acc = __builtin_amdgcn_mfma_f32_32x32x16_bf16(af, as_s8(braw), acc, 0, 0, 0);
                }
                b0 = n0; b1 = n1; b2 = n2; b3 = n3;
                n0 = p0; n1 = p1; n2 = p2; n3 = p3;
            }
            accP[c] = acc;
        }
    }

    __syncthreads();
    if (wid == 0) {
#pragma unroll
        for (int nt = 0; nt < 3; ++nt)
#pragma unroll
            for (int r = 0; r < 16; ++r) {
                int row = (r & 3) + 8 * (r >> 2) + 4 * half;
                smem[row * 96 + nt * 32 + m] = accA[nt][r];
            }
    }
    if (wid == 2) {
#pragma unroll
        for (int c = 0; c < 3; ++c)
#pragma unroll
            for (int r = 0; r < 16; ++r) {
                int row = (r & 3) + 8 * (r >> 2) + 4 * half;
                smem[3072 + row * 96 + m * 3 + c] = accP[c][r];
            }
    }
    __syncthreads();
    if (wid == 1) {
#pragma unroll
        for (int nt = 0; nt < 3; ++nt)
#pragma unroll
            for (int r = 0; r < 16; ++r) {
                int row = (r & 3) + 8 * (r >> 2) + 4 * half;
                smem[row * 96 + nt * 32 + m] += accA[nt][r];
            }
    }
    if (wid == 3) {
#pragma unroll
        for (int c = 0; c < 3; ++c)
#pragma unroll
            for (int r = 0; r < 16; ++r) {
                int row = (r & 3) + 8 * (r >> 2) + 4 * half;
                smem[3072 + row * 96 + m * 3 + c] += accP[c][r];
            }
    }
    __syncthreads();
    for (int i = tid; i < 3072; i += 256) {
        int n = base + i / 96;
        if (n < N) SOUT[(size_t)n * 96 + i % 96] = smem[i];
    }
    for (int i = tid; i < 3072; i += 256) {
        int n = base + i / 96;
        if (n < N) VOUT[(size_t)n * 96 + i % 96] = smem[3072 + i];
    }
}

// ============ K5: gate + lin2 + residual (VERIFIED) ============
__global__ void k5(const float* __restrict__ SOUT, const float* __restrict__ VOUT,
                   const float* __restrict__ ns, const float* __restrict__ nv,
                   const float* __restrict__ L2s, const float* __restrict__ L2v,
                   float* __restrict__ out, int N)
{
    __shared__ float sLs[64 * 64];
    __shared__ float sLv[32 * 32];
    __shared__ float sGS[4][64];
    __shared__ float sGV[4][96];
    int tid = threadIdx.x;
    for (int i = tid; i < 64 * 64; i += 256) sLs[i] = L2s[i];
    for (int i = tid; i < 32 * 32; i += 256) sLv[i] = L2v[i];
    __syncthreads();
    int wid = tid >> 6, lane = tid & 63;
    int gw = blockIdx.x * 4 + wid, nw = gridDim.x * 4;
    for (int n = gw; n < N; n += nw) {
        float so = SOUT[(size_t)n * 96 + lane];
        float sig = 0.f;
        if (lane < 32) sig = sigmoidf_(SOUT[(size_t)n * 96 + 64 + lane]);
        float sigA = __shfl(sig, lane / 3);
        float sigB = __shfl(sig, (64 + lane) / 3);
        sGS[wid][lane] = so * sigmoidf_(so);
        float v0 = VOUT[(size_t)n * 96 + lane];
        sGV[wid][lane] = v0 * sigA;
        if (lane < 32) {
            float v1 = VOUT[(size_t)n * 96 + 64 + lane];
            sGV[wid][64 + lane] = v1 * sigB;
        }
        float acc = 0.f;
        for (int u = 0; u < 64; ++u) acc += sGS[wid][u] * sLs[u * 64 + lane];
        out[(size_t)n * 64 + lane] = ns[(size_t)n * 64 + lane] + C_LIN_S * acc;
        if (lane < 32) {
            float a0 = 0.f, a1 = 0.f, a2 = 0.f;
            for (int u = 0; u < 32; ++u) {
                float wv = sLv[u * 32 + lane];
                a0 += sGV[wid][u * 3 + 0] * wv;
                a1 += sGV[wid][u * 3 + 1] * wv;
                a2 += sGV[wid][u * 3 + 2] * wv;
            }
            size_t ob = (size_t)N * 64 + (size_t)n * 96 + lane * 3;
            out[ob + 0] = nv[(size_t)n * 96 + lane * 3 + 0] + C_LIN_V * a0;
            out[ob + 1] = nv[(size_t)n * 96 + lane * 3 + 1] + C_LIN_V * a1;
            out[ob + 2] = nv[(size_t)n * 96 + lane * 3 + 2] + C_LIN_V * a2;
        }
    }
}

extern "C" void kernel_launch(void* const* d_in, const int* in_sizes, int n_in,
                              void* d_out, int out_size, void* d_ws, size_t ws_size,
                              hipStream_t stream)
{
    const float* node_s = (const float*)d_in[0];
    const float* node_v = (const float*)d_in[1];
    const float4* esh   = (const float4*)d_in[2];
    const int* erow     = (const int*)d_in[4];
    const int* ecol     = (const int*)d_in[5];
    const float* W1ss   = (const float*)d_in[6];
    const float* W1vv   = (const float*)d_in[7];
    const float* W1sv   = (const float*)d_in[8];
    const float* W1vs   = (const float*)d_in[9];
    const float* L1s    = (const float*)d_in[10];
    const float* L1v    = (const float*)d_in[11];
    const float* W2ss   = (const float*)d_in[12];
    const float* W2vv   = (const float*)d_in[13];
    const float* W2sv   = (const float*)d_in[14];
    const float* W2vs   = (const float*)d_in[15];
    const float* L2s    = (const float*)d_in[16];
    const float* L2v    = (const float*)d_in[17];
    int N = in_sizes[0] / 64;
    int E = in_sizes[4];

    char* ws = (char*)d_ws;
    float* AGG            = (float*)ws;                                   // N*160 f32
    unsigned short* PREb  = (unsigned short*)(ws + (size_t)N * 640);      // N*512 bf16
    float* SOUT           = (float*)(ws + (size_t)N * 640);               // aliases PREb (dead then)
    float* VOUT           = (float*)(ws + (size_t)N * 640 + (size_t)N * 384);
    unsigned short* WT    = (unsigned short*)(ws + (size_t)N * 1664);     // 819200 bf16
    int* EJ               = (int*)(ws + (size_t)N * 1664 + 1638400);      // E int
    float4* ESHS          = (float4*)((char*)EJ + (size_t)E * 4);         // E float4
    int* CNT              = (int*)((char*)ESHS + (size_t)E * 16);         // N int
    int* OFFS             = CNT + N;                                      // N+16 int
    int* CUR              = OFFS + N + 16;                                // N int

    hipMemsetAsync(CNT, 0, (size_t)(3 * N + 16) * 4, stream);
    k_pre<<<(N + 31) / 32, 256, 0, stream>>>(node_s, node_v, W1ss, W1vv, W1sv, W1vs, PREb, N);
    k_hist<<<(E + 255) / 256, 256, 0, stream>>>(erow, CNT, E);
    k_scan<<<1, 1024, 0, stream>>>(CNT, OFFS, N, E);
    k_scatter<<<(E + 255) / 256, 256, 0, stream>>>(erow, ecol, esh, OFFS, CUR, EJ, ESHS, E);
    k_agg<<<(N + 3) / 4, 256, 0, stream>>>(PREb, EJ, ESHS, OFFS, AGG, N);
    k_lin1<<<1024, 256, 0, stream>>>(AGG, L1s, L1v, N);
    k_wprep<<<3200, 256, 0, stream>>>(W2ss, W2vv, W2sv, W2vs, WT);
    k4ab_mfma<<<(N + 31) / 32, 256, 0, stream>>>(node_s, node_v, AGG, WT, SOUT, VOUT, N);
    k5<<<1024, 256, 0, stream>>>(SOUT, VOUT, node_s, node_v, L2s, L2v, (float*)d_out, N);
}

// Round 17
// 716.636 us; speedup vs baseline: 1.3528x; 1.0200x over previous
//
#include <hip/hip_runtime.h>
#include <math.h>

// ---- constants from the reference ----
#define C_TP1_SS   0.125f          // 1/sqrt(64*1)
#define C_TP1_VV   0.1020620726f   // (1/sqrt(3))/sqrt(32*1)
#define C_TP1_SV   0.125f          // 1/sqrt(64*1)
#define C_TP1_VS   0.1767766953f   // 1/sqrt(32*1)
#define C_LIN_S    0.125f          // 1/sqrt(64)
#define C_LIN_V    0.1767766953f   // 1/sqrt(32)
#define C_TP2_SS   0.015625f       // 1/sqrt(64*64)
#define C_TP2_VV   0.0180421959f   // (1/sqrt(3))/32
#define C_TP2_SVVS 0.0220970869f   // 1/sqrt(2048)

typedef __attribute__((ext_vector_type(8))) short short8;
typedef __attribute__((ext_vector_type(16))) float f32x16;

__device__ __forceinline__ float sigmoidf_(float x) { return 1.f / (1.f + __expf(-x)); }

__device__ __forceinline__ unsigned short f2bf(float f) {
    unsigned int x = __float_as_uint(f);
    unsigned int r = x + 0x7FFFu + ((x >> 16) & 1u);
    return (unsigned short)(r >> 16);
}

__device__ __forceinline__ unsigned int pack2(float lo, float hi) {
    unsigned int r;
    asm("v_cvt_pk_bf16_f32 %0, %1, %2" : "=v"(r) : "v"(lo), "v"(hi));
    return r;
}

__device__ __forceinline__ float blo(unsigned int v) { return __uint_as_float(v << 16); }
__device__ __forceinline__ float bhi(unsigned int v) { return __uint_as_float(v & 0xffff0000u); }

__device__ __forceinline__ short8 as_s8(int4 v) { union { int4 a; short8 b; } u_; u_.a = v; return u_.b; }

__device__ __forceinline__ short8 pack8(float a0, float a1, float a2, float a3,
                                        float a4, float a5, float a6, float a7) {
    union { int i[4]; short8 s; } u_;
    asm("v_cvt_pk_bf16_f32 %0, %1, %2" : "=v"(u_.i[0]) : "v"(a0), "v"(a1));
    asm("v_cvt_pk_bf16_f32 %0, %1, %2" : "=v"(u_.i[1]) : "v"(a2), "v"(a3));
    asm("v_cvt_pk_bf16_f32 %0, %1, %2" : "=v"(u_.i[2]) : "v"(a4), "v"(a5));
    asm("v_cvt_pk_bf16_f32 %0, %1, %2" : "=v"(u_.i[3]) : "v"(a6), "v"(a7));
    return u_.s;
}

// bf16-staging loaders (element offset must be 4-aligned for ld4bf)
__device__ __forceinline__ float4 ld4bf(const unsigned short* p) {
    uint2 v = *(const uint2*)p;
    float4 r;
    r.x = __uint_as_float(v.x << 16);
    r.y = __uint_as_float(v.x & 0xffff0000u);
    r.z = __uint_as_float(v.y << 16);
    r.w = __uint_as_float(v.y & 0xffff0000u);
    return r;
}
__device__ __forceinline__ float ldbf(const unsigned short* p) {
    return __uint_as_float(((unsigned int)*p) << 16);
}

// ============ K_pre v3: tiled GEMM, outputs bf16 PREb with tp1 constants folded (VERIFIED) ============
__global__ __launch_bounds__(256, 2) void k_pre(const float* __restrict__ ns, const float* __restrict__ nv,
                                                const float* __restrict__ Wss, const float* __restrict__ Wvv,
                                                const float* __restrict__ Wsv, const float* __restrict__ Wvs,
                                                unsigned short* __restrict__ PREb, int N)
{
    __shared__ float smem[17728];
    float* sWss = smem;            // 6144
    float* sWvv = smem + 6144;     // 3072
    float* sWsv = smem + 9216;     // 2048
    float* sWvs = smem + 11264;    // 1024
    float* nsT  = smem + 12288;    // 64*34
    float* nvT  = smem + 14464;    // 96*34
    int tid = threadIdx.x;
    int base = blockIdx.x * 32;

    for (int i = tid; i < 6144; i += 256) sWss[i] = Wss[i];
    for (int i = tid; i < 3072; i += 256) sWvv[i] = Wvv[i];
    for (int i = tid; i < 2048; i += 256) sWsv[i] = Wsv[i];
    for (int i = tid; i < 1024; i += 256) sWvs[i] = Wvs[i];
    for (int i = tid; i < 2048; i += 256) {
        int m = i >> 6, u = i & 63;
        int n = base + m;
        nsT[u * 34 + m] = (n < N) ? ns[(size_t)n * 64 + u] : 0.f;
    }
    for (int i = tid; i < 3072; i += 256) {
        int m = i / 96, f = i % 96;
        int u = f / 3, c = f % 3;
        int n = base + m;
        nvT[(c * 32 + u) * 34 + m] = (n < N) ? nv[(size_t)n * 96 + f] : 0.f;
    }
    __syncthreads();

    int tx = tid & 15, ty = tid >> 4;
    int m2 = tx * 2;
    int e6 = ty * 6, e2 = ty * 2;

    float pP[2][6] = {};
    float pQ[2][6][3] = {};
    float pS[2][2] = {};
    float pV[2][2][3] = {};

    for (int u = 0; u < 64; ++u) {
        float2 x = *(const float2*)&nsT[u * 34 + m2];
        float w6[6];
        *(float2*)&w6[0] = *(const float2*)&sWss[u * 96 + e6 + 0];
        *(float2*)&w6[2] = *(const float2*)&sWss[u * 96 + e6 + 2];
        *(float2*)&w6[4] = *(const float2*)&sWss[u * 96 + e6 + 4];
        float2 w2 = *(const float2*)&sWsv[u * 32 + e2];
#pragma unroll
        for (int j = 0; j < 6; ++j) { pP[0][j] += x.x * w6[j]; pP[1][j] += x.y * w6[j]; }
        pS[0][0] += x.x * w2.x; pS[0][1] += x.x * w2.y;
        pS[1][0] += x.y * w2.x; pS[1][1] += x.y * w2.y;
    }
    for (int u = 0; u < 32; ++u) {
        float2 x0 = *(const float2*)&nvT[(0 * 32 + u) * 34 + m2];
        float2 x1 = *(const float2*)&nvT[(1 * 32 + u) * 34 + m2];
        float2 x2 = *(const float2*)&nvT[(2 * 32 + u) * 34 + m2];
        float w6[6];
        *(float2*)&w6[0] = *(const float2*)&sWvv[u * 96 + e6 + 0];
        *(float2*)&w6[2] = *(const float2*)&sWvv[u * 96 + e6 + 2];
        *(float2*)&w6[4] = *(const float2*)&sWvv[u * 96 + e6 + 4];
        float2 w2 = *(const float2*)&sWvs[u * 32 + e2];
#pragma unroll
        for (int j = 0; j < 6; ++j) {
            pQ[0][j][0] += x0.x * w6[j]; pQ[1][j][0] += x0.y * w6[j];
            pQ[0][j][1] += x1.x * w6[j]; pQ[1][j][1] += x1.y * w6[j];
            pQ[0][j][2] += x2.x * w6[j]; pQ[1][j][2] += x2.y * w6[j];
        }
        pV[0][0][0] += x0.x * w2.x; pV[0][1][0] += x0.x * w2.y;
        pV[1][0][0] += x0.y * w2.x; pV[1][1][0] += x0.y * w2.y;
        pV[0][0][1] += x1.x * w2.x; pV[0][1][1] += x1.x * w2.y;
        pV[1][0][1] += x1.y * w2.x; pV[1][1][1] += x1.y * w2.y;
        pV[0][0][2] += x2.x * w2.x; pV[0][1][2] += x2.x * w2.y;
        pV[1][0][2] += x2.y * w2.x; pV[1][1][2] += x2.y * w2.y;
    }

    __syncthreads();
    unsigned short* PT = (unsigned short*)smem;   // [32][512] ushort
#pragma unroll
    for (int m = 0; m < 2; ++m) {
        int nr = m2 + m;
#pragma unroll
        for (int j = 0; j < 6; ++j) {
            int e = e6 + j;
            unsigned int lo = pack2(C_TP1_SS * pP[m][j], C_TP1_VV * pQ[m][j][0]);
            unsigned int hi = pack2(C_TP1_VV * pQ[m][j][1], C_TP1_VV * pQ[m][j][2]);
            *(uint2*)&PT[nr * 512 + e * 4] = make_uint2(lo, hi);
        }
#pragma unroll
        for (int j = 0; j < 2; ++j) {
            int w = e2 + j;
            unsigned int lo = pack2(C_TP1_SV * pS[m][j], C_TP1_VS * pV[m][j][0]);
            unsigned int hi = pack2(C_TP1_VS * pV[m][j][1], C_TP1_VS * pV[m][j][2]);
            *(uint2*)&PT[nr * 512 + (96 + w) * 4] = make_uint2(lo, hi);
        }
    }
    __syncthreads();
    for (int i = tid; i < 2048; i += 256) {
        int n = base + (i >> 6);
        if (n < N) ((int4*)PREb)[(size_t)base * 64 + i] = ((const int4*)PT)[i];
    }
}

// ============ CSR build: histogram -> scan -> scatter (VERIFIED) ============
__global__ void k_hist(const int* __restrict__ erow, int* __restrict__ CNT, int E)
{
    int e = blockIdx.x * 256 + threadIdx.x;
    if (e < E) atomicAdd(&CNT[erow[e]], 1);
}

__global__ void k_scan(const int* __restrict__ CNT, int* __restrict__ OFFS, int N, int E)
{
    __shared__ int part[1024];
    int t = threadIdx.x;
    int chunk = (N + 1023) >> 10;
    int b0 = t * chunk; if (b0 > N) b0 = N;
    int b1 = b0 + chunk; if (b1 > N) b1 = N;
    int s = 0;
    for (int i = b0; i < b1; ++i) s += CNT[i];
    part[t] = s;
    __syncthreads();
    for (int off = 1; off < 1024; off <<= 1) {
        int v = (t >= off) ? part[t - off] : 0;
        __syncthreads();
        part[t] += v;
        __syncthreads();
    }
    int run = part[t] - s;
    for (int i = b0; i < b1; ++i) { OFFS[i] = run; run += CNT[i]; }
    if (t == 1023) OFFS[N] = E;
}

__global__ void k_scatter(const int* __restrict__ erow, const int* __restrict__ ecol,
                          const float4* __restrict__ esh, const int* __restrict__ OFFS,
                          int* __restrict__ CUR, int* __restrict__ EJ,
                          float4* __restrict__ ESHS, int E)
{
    int e = blockIdx.x * 256 + threadIdx.x;
    if (e >= E) return;
    int r = erow[e];
    int p = OFFS[r] + atomicAdd(&CUR[r], 1);
    EJ[p] = ecol[e];
    ESHS[p] = esh[e];
}

// ============ K_agg v2: depth-2 software pipeline over the edge list ============
// Same per-edge math and accumulation order as VERIFIED k_agg; the (j,sh) for edge
// i+1 and the gather for edge i+1 are issued before computing edge i.
__global__ void k_agg(const unsigned short* __restrict__ PREb, const int* __restrict__ EJ,
                      const float4* __restrict__ ESHS, const int* __restrict__ OFFS,
                      float* __restrict__ AGG, int N)
{
    int wv = blockIdx.x * 4 + (threadIdx.x >> 6);
    if (wv >= N) return;
    int lane = threadIdx.x & 63;
    int beg = OFFS[wv], end = OFFS[wv + 1];
    const int4* pb = (const int4*)PREb;
    float a0 = 0.f, a1 = 0.f;
    float b00 = 0.f, b01 = 0.f, b02 = 0.f, b10 = 0.f, b11 = 0.f, b12 = 0.f;
    int gsrc = (lane >= 48) ? (lane - 16) : lane;

    int   j1 = 0;
    float4 sh0 = make_float4(0.f, 0.f, 0.f, 0.f), sh1 = sh0;
    int4  g0 = make_int4(0, 0, 0, 0);
    if (beg < end) {
        int j0 = EJ[beg];
        sh0 = ESHS[beg];
        g0 = pb[(size_t)j0 * 64 + lane];
    }
    if (beg + 1 < end) {
        j1 = EJ[beg + 1];
        sh1 = ESHS[beg + 1];
    }
    for (int i = beg; i < end; ++i) {
        float4 sh = sh0;
        int4 g = g0;
        if (i + 1 < end) {
            g0 = pb[(size_t)j1 * 64 + lane];
            sh0 = sh1;
            if (i + 2 < end) {
                j1 = EJ[i + 2];
                sh1 = ESHS[i + 2];
            }
        }
        unsigned int gx = (unsigned int)g.x, gy = (unsigned int)g.y;
        unsigned int gz = (unsigned int)g.z, gw = (unsigned int)g.w;
        float P0 = blo(gx), Q00 = bhi(gx), Q01 = blo(gy), Q02 = bhi(gy);
        float P1 = blo(gz), Q10 = bhi(gz), Q11 = blo(gw), Q12 = bhi(gw);
        float ms0 = sh.x * P0 + sh.y * Q00 + sh.z * Q01 + sh.w * Q02;
        float ms1 = sh.x * P1 + sh.y * Q10 + sh.z * Q11 + sh.w * Q12;
        float sg0 = sigmoidf_(ms0);
        float sg1 = sigmoidf_(ms1);
        float sw0 = __shfl(sg0, gsrc);
        float sw1 = __shfl(sg1, gsrc);
        if (lane < 32) {
            a0 += ms0 * sg0;
            a1 += ms1 * sg1;
        } else if (lane >= 48) {
            b00 += (sh.y * P0 + sh.x * Q00) * sw0;
            b01 += (sh.z * P0 + sh.x * Q01) * sw0;
            b02 += (sh.w * P0 + sh.x * Q02) * sw0;
            b10 += (sh.y * P1 + sh.x * Q10) * sw1;
            b11 += (sh.z * P1 + sh.x * Q11) * sw1;
            b12 += (sh.w * P1 + sh.x * Q12) * sw1;
        }
    }
    float* ab = AGG + (size_t)wv * 160;
    if (lane < 32) {
        *(float2*)&ab[2 * lane] = make_float2(a0, a1);
    } else if (lane >= 48) {
        int o = 64 + 6 * (lane - 48);
        *(float2*)&ab[o + 0] = make_float2(b00, b01);
        *(float2*)&ab[o + 2] = make_float2(b02, b10);
        *(float2*)&ab[o + 4] = make_float2(b11, b12);
    }
}

// ============ K_lin1: apply lin1 to aggregates, in place (VERIFIED) ============
__global__ void k_lin1(float* __restrict__ AGG, const float* __restrict__ L1s,
                       const float* __restrict__ L1v, int N)
{
    __shared__ float sLs[64 * 64];
    __shared__ float sLv[32 * 32];
    __shared__ float sS[4][64];
    __shared__ float sV[4][96];
    int tid = threadIdx.x;
    for (int i = tid; i < 64 * 64; i += 256) sLs[i] = L1s[i];
    for (int i = tid; i < 32 * 32; i += 256) sLv[i] = L1v[i];
    __syncthreads();
    int wid = tid >> 6, lane = tid & 63;
    int gw = blockIdx.x * 4 + wid, nw = gridDim.x * 4;
    for (int n = gw; n < N; n += nw) {
        float* base = AGG + (size_t)n * 160;
        sS[wid][lane] = base[lane];
        sV[wid][lane] = base[64 + lane];
        if (lane < 32) sV[wid][64 + lane] = base[128 + lane];
        float acc = 0.f;
        for (int u = 0; u < 64; ++u) acc += sS[wid][u] * sLs[u * 64 + lane];
        float o0 = 0.f, o1 = 0.f, o2 = 0.f;
        if (lane < 32) {
            for (int u = 0; u < 32; ++u) {
                float wv = sLv[u * 32 + lane];
                o0 += sV[wid][u * 3 + 0] * wv;
                o1 += sV[wid][u * 3 + 1] * wv;
                o2 += sV[wid][u * 3 + 2] * wv;
            }
        }
        base[lane] = C_LIN_S * acc;
        if (lane < 32) {
            base[64 + lane * 3 + 0] = C_LIN_V * o0;
            base[64 + lane * 3 + 1] = C_LIN_V * o1;
            base[64 + lane * 3 + 2] = C_LIN_V * o2;
        }
    }
}

// ============ K_wprep v4: ALL regions in swizzled per-lane fragment order (VERIFIED r14) ============
__global__ void k_wprep(const float* __restrict__ W2ss, const float* __restrict__ W2vv,
                        const float* __restrict__ W2sv, const float* __restrict__ W2vs,
                        unsigned short* __restrict__ WT)
{
    int i = blockIdx.x * 256 + threadIdx.x;
    if (i >= 819200) return;
    float val;
    if (i < 393216) {
        int nt = i / 131072;
        int r  = i % 131072;
        int kb = r >> 9;
        int q  = r & 511;
        int lane = q >> 3, j = q & 7;
        int w = nt * 32 + (lane & 31);
        int k = kb * 16 + (lane >> 5) * 8 + j;
        val = W2ss[(size_t)k * 96 + w] * C_TP2_SS;
    } else if (i < 688128) {
        int ii = i - 393216;
        int nt = ii / 98304;
        int r  = ii % 98304;
        int kb = r >> 9;
        int q  = r & 511;
        int lane = q >> 3, j = q & 7;
        int w = nt * 32 + (lane & 31);
        int k = kb * 16 + (lane >> 5) * 8 + j;
        int q2 = k & 1023;
        val = W2vv[(size_t)q2 * 96 + w] * C_TP2_VV;
    } else if (i < 753664) {
        int ii = i - 688128;
        int kb = ii >> 9;
        int q  = ii & 511;
        int lane = q >> 3, j = q & 7;
        int w = lane & 31;
        int k = kb * 16 + (lane >> 5) * 8 + j;
        val = W2sv[(size_t)k * 32 + w] * C_TP2_SVVS;
    } else {
        int ii = i - 753664;
        int kb = ii >> 9;
        int q  = ii & 511;
        int lane = q >> 3, j = q & 7;
        int w = lane & 31;
        int k = kb * 16 + (lane >> 5) * 8 + j;
        val = W2vs[(size_t)k * 32 + w] * C_TP2_SVVS;
    }
    WT[i] = f2bf(val);
}

// ============ K4ab_mfma v11 (VERIFIED r16): bf16 staging, swizzled B, launch_bounds(256,4) ============
#define OFF_NS 0
#define OFF_AS 2176
#define OFF_NV 4352
#define OFF_AV 7552
__global__ __launch_bounds__(256, 4) void k4ab_mfma(const float* __restrict__ ns, const float* __restrict__ nv,
                                                    const float* __restrict__ AGG,
                                                    const unsigned short* __restrict__ WT,
                                                    float* __restrict__ SOUT, float* __restrict__ VOUT, int N)
{
    __shared__ float smem[6144];            // 24.6 KB: staging (bf16 overlay) then epilogue
    unsigned short* stg = (unsigned short*)smem;
    const unsigned short* Wt_ss = WT;
    const unsigned short* Wt_vv = WT + 393216;
    const unsigned short* Wt_sv = WT + 688128;
    const unsigned short* Wt_vs = WT + 753664;

    int tid = threadIdx.x;
    int base = blockIdx.x * 32;

    for (int i = tid; i < 2048; i += 256) {
        int mm = i >> 6, u = i & 63;
        int n = base + mm;
        stg[OFF_NS + mm * 68 + u] = f2bf((n < N) ? ns[(size_t)n * 64 + u] : 0.f);
        stg[OFF_AS + mm * 68 + u] = f2bf((n < N) ? AGG[(size_t)n * 160 + u] : 0.f);
    }
    for (int i = tid; i < 3072; i += 256) {
        int mm = i / 96, r = i % 96;
        int c = r >> 5, q = r & 31;
        int n = base + mm;
        stg[OFF_NV + mm * 100 + r] = f2bf((n < N) ? nv[(size_t)n * 96 + q * 3 + c] : 0.f);
        stg[OFF_AV + mm * 100 + r] = f2bf((n < N) ? AGG[(size_t)n * 160 + 64 + q * 3 + c] : 0.f);
    }
    __syncthreads();

    int wid = tid >> 6;
    int l = tid & 63;
    int m = l & 31;
    int half = l >> 5;
    const unsigned short* pns = stg + OFF_NS + m * 68;
    const unsigned short* pas = stg + OFF_AS + m * 68;
    const unsigned short* pnv = stg + OFF_NV + m * 100;
    const unsigned short* pav = stg + OFF_AV + m * 100;

    f32x16 accA[3];
    f32x16 accP[3];
#pragma unroll
    for (int a = 0; a < 3; ++a) {
#pragma unroll
        for (int r = 0; r < 16; ++r) { accA[a][r] = 0.f; accP[a][r] = 0.f; }
    }

    if (wid == 0) {
        float4 ys[4][2];
#pragma unroll
        for (int t = 0; t < 4; ++t) {
            ys[t][0] = ld4bf(&pas[t * 16 + half * 8]);
            ys[t][1] = ld4bf(&pas[t * 16 + half * 8 + 4]);
        }
        const int4* wb = (const int4*)Wt_ss + l;
        for (int u0 = 0; u0 < 64; u0 += 4) {
            float4 x4 = ld4bf(&pns[u0]);
#pragma unroll
            for (int uu = 0; uu < 4; ++uu) {
                float x = (uu == 0) ? x4.x : (uu == 1) ? x4.y : (uu == 2) ? x4.z : x4.w;
                const int4* wu = wb + (u0 + uu) * 256;
                int4 b[4];
#pragma unroll
                for (int t = 0; t < 4; ++t) b[t] = wu[t * 64];
                short8 af[4];
#pragma unroll
                for (int t = 0; t < 4; ++t)
                    af[t] = pack8(x * ys[t][0].x, x * ys[t][0].y, x * ys[t][0].z, x * ys[t][0].w,
                                  x * ys[t][1].x, x * ys[t][1].y, x * ys[t][1].z, x * ys[t][1].w);
#pragma unroll
                for (int nt = 0; nt < 3; ++nt) {
                    int4 nb[4];
                    if (nt < 2) {
#pragma unroll
                        for (int t = 0; t < 4; ++t) nb[t] = wu[(nt + 1) * 16384 + t * 64];
                    }
#pragma unroll
                    for (int t = 0; t < 4; ++t)
                        accA[nt] = __builtin_amdgcn_mfma_f32_32x32x16_bf16(af[t], as_s8(b[t]), accA[nt], 0, 0, 0);
                    if (nt < 2) {
#pragma unroll
                        for (int t = 0; t < 4; ++t) b[t] = nb[t];
                    }
                }
            }
        }
    } else if (wid == 1) {
        float4 yv[3][2][2];
#pragma unroll
        for (int c = 0; c < 3; ++c)
#pragma unroll
            for (int t = 0; t < 2; ++t) {
                yv[c][t][0] = ld4bf(&pav[c * 32 + t * 16 + half * 8]);
                yv[c][t][1] = ld4bf(&pav[c * 32 + t * 16 + half * 8 + 4]);
            }
        const int4* wb = (const int4*)Wt_vv + l;
#pragma unroll
        for (int c = 0; c < 3; ++c) {
            for (int u0 = 0; u0 < 32; u0 += 4) {
                float4 x4 = ld4bf(&pnv[c * 32 + u0]);
#pragma unroll
                for (int uu = 0; uu < 4; ++uu) {
                    float x = (uu == 0) ? x4.x : (uu == 1) ? x4.y : (uu == 2) ? x4.z : x4.w;
                    const int4* wu = wb + c * 4096 + (u0 + uu) * 128;
                    int4 b[2];
                    b[0] = wu[0];
                    b[1] = wu[64];
                    short8 af[2];
#pragma unroll
                    for (int t = 0; t < 2; ++t)
                        af[t] = pack8(x * yv[c][t][0].x, x * yv[c][t][0].y, x * yv[c][t][0].z, x * yv[c][t][0].w,
                                      x * yv[c][t][1].x, x * yv[c][t][1].y, x * yv[c][t][1].z, x * yv[c][t][1].w);
#pragma unroll
                    for (int nt = 0; nt < 3; ++nt) {
                        int4 nb[2];
                        if (nt < 2) {
                            nb[0] = wu[(nt + 1) * 12288];
                            nb[1] = wu[(nt + 1) * 12288 + 64];
                        }
                        accA[nt] = __builtin_amdgcn_mfma_f32_32x32x16_bf16(af[0], as_s8(b[0]), accA[nt], 0, 0, 0);
                        accA[nt] = __builtin_amdgcn_mfma_f32_32x32x16_bf16(af[1], as_s8(b[1]), accA[nt], 0, 0, 0);
                        if (nt < 2) { b[0] = nb[0]; b[1] = nb[1]; }
                    }
                }
            }
        }
    } else if (wid == 2) {
        float4 yv[3][2][2];
#pragma unroll
        for (int c = 0; c < 3; ++c)
#pragma unroll
            for (int t = 0; t < 2; ++t) {
                yv[c][t][0] = ld4bf(&pav[c * 32 + t * 16 + half * 8]);
                yv[c][t][1] = ld4bf(&pav[c * 32 + t * 16 + half * 8 + 4]);
            }
        const int4* bp = (const int4*)Wt_sv + l;
#pragma unroll
        for (int c = 0; c < 3; ++c) {
            f32x16 acc;
#pragma unroll
            for (int r = 0; r < 16; ++r) acc[r] = 0.f;
            int4 b0 = bp[0], b1 = bp[64];
            int4 n0 = bp[128], n1 = bp[192];
            for (int u = 0; u < 64; ++u) {
                int up = (u + 2 < 64) ? (u + 2) : 63;
                const int4* bq = bp + up * 128;
                int4 p0 = bq[0], p1 = bq[64];
                float x = ldbf(&pns[u]);
#pragma unroll
                for (int t = 0; t < 2; ++t) {
                    short8 af = pack8(x * yv[c][t][0].x, x * yv[c][t][0].y, x * yv[c][t][0].z, x * yv[c][t][0].w,
                                      x * yv[c][t][1].x, x * yv[c][t][1].y, x * yv[c][t][1].z, x * yv[c][t][1].w);
                    int4 braw = (t == 0) ? b0 : b1;
                    acc = __builtin_amdgcn_mfma_f32_32x32x16_bf16(af, as_s8(braw), acc, 0, 0, 0);
                }
                b0 = n0; b1 = n1;
                n0 = p0; n1 = p1;
            }
            accP[c] = acc;
        }
    } else {
        float4 ys[4][2];
#pragma unroll
        for (int t = 0; t < 4; ++t) {
            ys[t][0] = ld4bf(&pas[t * 16 + half * 8]);
            ys[t][1] = ld4bf(&pas[t * 16 + half * 8 + 4]);
        }
        const int4* bp = (const int4*)Wt_vs + l;
#pragma unroll
        for (int c = 0; c < 3; ++c) {
            f32x16 acc;
#pragma unroll
            for (int r = 0; r < 16; ++r) acc[r] = 0.f;
            int4 b0 = bp[0], b1 = bp[64], b2 = bp[128], b3 = bp[192];
            int4 n0 = bp[256], n1 = bp[320], n2 = bp[384], n3 = bp[448];
            for (int u = 0; u < 32; ++u) {
                int up = (u + 2 < 32) ? (u + 2) : 31;
                const int4* bq = bp + up * 256;
                int4 p0 = bq[0], p1 = bq[64], p2 = bq[128], p3 = bq[192];
                float x = ldbf(&pnv[c * 32 + u]);
#pragma unroll
                for (int t = 0; t < 4; ++t) {
                    short8 af = pack8(x * ys[t][0].x, x * ys[t][0].y, x * ys[t][0].z, x * ys[t][0].w,
                                      x * ys[t][1].x, x * ys[t][1].y, x * ys[t][1].z, x * ys[t][1].w);
                    int4 braw = (t == 0) ? b0 : (t == 1) ? b1 : (t == 2) ? b2 : b3;
                    acc = __builtin_amdgcn_mfma_f32_32x32x16_bf16(af, as_s8(braw), acc, 0, 0, 0);
                }
                b0 = n0; b1 = n1; b2 = n2; b3 = n3;
                n0 = p0; n1 = p1; n2 = p2; n3 = p3;
            }
            accP[c] = acc;
        }
    }

    __syncthreads();
    if (wid == 0) {
#pragma unroll
        for (int nt = 0; nt < 3; ++nt)
#pragma unroll
            for (int r = 0; r < 16; ++r) {
                int row = (r & 3) + 8 * (r >> 2) + 4 * half;
                smem[row * 96 + nt * 32 + m] = accA[nt][r];
            }
    }
    if (wid == 2) {
#pragma unroll
        for (int c = 0; c < 3; ++c)
#pragma unroll
            for (int r = 0; r < 16; ++r) {
                int row = (r & 3) + 8 * (r >> 2) + 4 * half;
                smem[3072 + row * 96 + m * 3 + c] = accP[c][r];
            }
    }
    __syncthreads();
    if (wid == 1) {
#pragma unroll
        for (int nt = 0; nt < 3; ++nt)
#pragma unroll
            for (int r = 0; r < 16; ++r) {
                int row = (r & 3) + 8 * (r >> 2) + 4 * half;
                smem[row * 96 + nt * 32 + m] += accA[nt][r];
            }
    }
    if (wid == 3) {
#pragma unroll
        for (int c = 0; c < 3; ++c)
#pragma unroll
            for (int r = 0; r < 16; ++r) {
                int row = (r & 3) + 8 * (r >> 2) + 4 * half;
                smem[3072 + row * 96 + m * 3 + c] += accP[c][r];
            }
    }
    __syncthreads();
    for (int i = tid; i < 3072; i += 256) {
        int n = base + i / 96;
        if (n < N) SOUT[(size_t)n * 96 + i % 96] = smem[i];
    }
    for (int i = tid; i < 3072; i += 256) {
        int n = base + i / 96;
        if (n < N) VOUT[(size_t)n * 96 + i % 96] = smem[3072 + i];
    }
}

// ============ K5: gate + lin2 + residual (VERIFIED) ============
__global__ void k5(const float* __restrict__ SOUT, const float* __restrict__ VOUT,
                   const float* __restrict__ ns, const float* __restrict__ nv,
                   const float* __restrict__ L2s, const float* __restrict__ L2v,
                   float* __restrict__ out, int N)
{
    __shared__ float sLs[64 * 64];
    __shared__ float sLv[32 * 32];
    __shared__ float sGS[4][64];
    __shared__ float sGV[4][96];
    int tid = threadIdx.x;
    for (int i = tid; i < 64 * 64; i += 256) sLs[i] = L2s[i];
    for (int i = tid; i < 32 * 32; i += 256) sLv[i] = L2v[i];
    __syncthreads();
    int wid = tid >> 6, lane = tid & 63;
    int gw = blockIdx.x * 4 + wid, nw = gridDim.x * 4;
    for (int n = gw; n < N; n += nw) {
        float so = SOUT[(size_t)n * 96 + lane];
        float sig = 0.f;
        if (lane < 32) sig = sigmoidf_(SOUT[(size_t)n * 96 + 64 + lane]);
        float sigA = __shfl(sig, lane / 3);
        float sigB = __shfl(sig, (64 + lane) / 3);
        sGS[wid][lane] = so * sigmoidf_(so);
        float v0 = VOUT[(size_t)n * 96 + lane];
        sGV[wid][lane] = v0 * sigA;
        if (lane < 32) {
            float v1 = VOUT[(size_t)n * 96 + 64 + lane];
            sGV[wid][64 + lane] = v1 * sigB;
        }
        float acc = 0.f;
        for (int u = 0; u < 64; ++u) acc += sGS[wid][u] * sLs[u * 64 + lane];
        out[(size_t)n * 64 + lane] = ns[(size_t)n * 64 + lane] + C_LIN_S * acc;
        if (lane < 32) {
            float a0 = 0.f, a1 = 0.f, a2 = 0.f;
            for (int u = 0; u < 32; ++u) {
                float wv = sLv[u * 32 + lane];
                a0 += sGV[wid][u * 3 + 0] * wv;
                a1 += sGV[wid][u * 3 + 1] * wv;
                a2 += sGV[wid][u * 3 + 2] * wv;
            }
            size_t ob = (size_t)N * 64 + (size_t)n * 96 + lane * 3;
            out[ob + 0] = nv[(size_t)n * 96 + lane * 3 + 0] + C_LIN_V * a0;
            out[ob + 1] = nv[(size_t)n * 96 + lane * 3 + 1] + C_LIN_V * a1;
            out[ob + 2] = nv[(size_t)n * 96 + lane * 3 + 2] + C_LIN_V * a2;
        }
    }
}

extern "C" void kernel_launch(void* const* d_in, const int* in_sizes, int n_in,
                              void* d_out, int out_size, void* d_ws, size_t ws_size,
                              hipStream_t stream)
{
    const float* node_s = (const float*)d_in[0];
    const float* node_v = (const float*)d_in[1];
    const float4* esh   = (const float4*)d_in[2];
    const int* erow     = (const int*)d_in[4];
    const int* ecol     = (const int*)d_in[5];
    const float* W1ss   = (const float*)d_in[6];
    const float* W1vv   = (const float*)d_in[7];
    const float* W1sv   = (const float*)d_in[8];
    const float* W1vs   = (const float*)d_in[9];
    const float* L1s    = (const float*)d_in[10];
    const float* L1v    = (const float*)d_in[11];
    const float* W2ss   = (const float*)d_in[12];
    const float* W2vv   = (const float*)d_in[13];
    const float* W2sv   = (const float*)d_in[14];
    const float* W2vs   = (const float*)d_in[15];
    const float* L2s    = (const float*)d_in[16];
    const float* L2v    = (const float*)d_in[17];
    int N = in_sizes[0] / 64;
    int E = in_sizes[4];

    char* ws = (char*)d_ws;
    float* AGG            = (float*)ws;                                   // N*160 f32
    unsigned short* PREb  = (unsigned short*)(ws + (size_t)N * 640);      // N*512 bf16
    float* SOUT           = (float*)(ws + (size_t)N * 640);               // aliases PREb (dead then)
    float* VOUT           = (float*)(ws + (size_t)N * 640 + (size_t)N * 384);
    unsigned short* WT    = (unsigned short*)(ws + (size_t)N * 1664);     // 819200 bf16
    int* EJ               = (int*)(ws + (size_t)N * 1664 + 1638400);      // E int
    float4* ESHS          = (float4*)((char*)EJ + (size_t)E * 4);         // E float4
    int* CNT              = (int*)((char*)ESHS + (size_t)E * 16);         // N int
    int* OFFS             = CNT + N;                                      // N+16 int
    int* CUR              = OFFS + N + 16;                                // N int

    hipMemsetAsync(CNT, 0, (size_t)(3 * N + 16) * 4, stream);
    k_pre<<<(N + 31) / 32, 256, 0, stream>>>(node_s, node_v, W1ss, W1vv, W1sv, W1vs, PREb, N);
    k_hist<<<(E + 255) / 256, 256, 0, stream>>>(erow, CNT, E);
    k_scan<<<1, 1024, 0, stream>>>(CNT, OFFS, N, E);
    k_scatter<<<(E + 255) / 256, 256, 0, stream>>>(erow, ecol, esh, OFFS, CUR, EJ, ESHS, E);
    k_agg<<<(N + 3) / 4, 256, 0, stream>>>(PREb, EJ, ESHS, OFFS, AGG, N);
    k_lin1<<<1024, 256, 0, stream>>>(AGG, L1s, L1v, N);
    k_wprep<<<3200, 256, 0, stream>>>(W2ss, W2vv, W2sv, W2vs, WT);
    k4ab_mfma<<<(N + 31) / 32, 256, 0, stream>>>(node_s, node_v, AGG, WT, SOUT, VOUT, N);
    k5<<<1024, 256, 0, stream>>>(SOUT, VOUT, node_s, node_v, L2s, L2v, (float*)d_out, N);
}

// Round 19
// 712.831 us; speedup vs baseline: 1.3600x; 1.0053x over previous
//
#include <hip/hip_runtime.h>
#include <math.h>

// ---- constants from the reference ----
#define C_TP1_SS   0.125f          // 1/sqrt(64*1)
#define C_TP1_VV   0.1020620726f   // (1/sqrt(3))/sqrt(32*1)
#define C_TP1_SV   0.125f          // 1/sqrt(64*1)
#define C_TP1_VS   0.1767766953f   // 1/sqrt(32*1)
#define C_LIN_S    0.125f          // 1/sqrt(64)
#define C_LIN_V    0.1767766953f   // 1/sqrt(32)
#define C_TP2_SS   0.015625f       // 1/sqrt(64*64)
#define C_TP2_VV   0.0180421959f   // (1/sqrt(3))/32
#define C_TP2_SVVS 0.0220970869f   // 1/sqrt(2048)

typedef __attribute__((ext_vector_type(8))) short short8;
typedef __attribute__((ext_vector_type(16))) float f32x16;

__device__ __forceinline__ float sigmoidf_(float x) { return 1.f / (1.f + __expf(-x)); }

__device__ __forceinline__ unsigned short f2bf(float f) {
    unsigned int x = __float_as_uint(f);
    unsigned int r = x + 0x7FFFu + ((x >> 16) & 1u);
    return (unsigned short)(r >> 16);
}

__device__ __forceinline__ unsigned int pack2(float lo, float hi) {
    unsigned int r;
    asm("v_cvt_pk_bf16_f32 %0, %1, %2" : "=v"(r) : "v"(lo), "v"(hi));
    return r;
}

__device__ __forceinline__ float blo(unsigned int v) { return __uint_as_float(v << 16); }
__device__ __forceinline__ float bhi(unsigned int v) { return __uint_as_float(v & 0xffff0000u); }

__device__ __forceinline__ short8 as_s8(int4 v) { union { int4 a; short8 b; } u_; u_.a = v; return u_.b; }

__device__ __forceinline__ short8 pack8(float a0, float a1, float a2, float a3,
                                        float a4, float a5, float a6, float a7) {
    union { int i[4]; short8 s; } u_;
    asm("v_cvt_pk_bf16_f32 %0, %1, %2" : "=v"(u_.i[0]) : "v"(a0), "v"(a1));
    asm("v_cvt_pk_bf16_f32 %0, %1, %2" : "=v"(u_.i[1]) : "v"(a2), "v"(a3));
    asm("v_cvt_pk_bf16_f32 %0, %1, %2" : "=v"(u_.i[2]) : "v"(a4), "v"(a5));
    asm("v_cvt_pk_bf16_f32 %0, %1, %2" : "=v"(u_.i[3]) : "v"(a6), "v"(a7));
    return u_.s;
}

// bf16-staging loaders (element offset must be 4-aligned for ld4bf)
__device__ __forceinline__ float4 ld4bf(const unsigned short* p) {
    uint2 v = *(const uint2*)p;
    float4 r;
    r.x = __uint_as_float(v.x << 16);
    r.y = __uint_as_float(v.x & 0xffff0000u);
    r.z = __uint_as_float(v.y << 16);
    r.w = __uint_as_float(v.y & 0xffff0000u);
    return r;
}
__device__ __forceinline__ float ldbf(const unsigned short* p) {
    return __uint_as_float(((unsigned int)*p) << 16);
}

// ============ K_pre v3: tiled GEMM, outputs bf16 PREb with tp1 constants folded (VERIFIED) ============
__global__ __launch_bounds__(256, 2) void k_pre(const float* __restrict__ ns, const float* __restrict__ nv,
                                                const float* __restrict__ Wss, const float* __restrict__ Wvv,
                                                const float* __restrict__ Wsv, const float* __restrict__ Wvs,
                                                unsigned short* __restrict__ PREb, int N)
{
    __shared__ float smem[17728];
    float* sWss = smem;            // 6144
    float* sWvv = smem + 6144;     // 3072
    float* sWsv = smem + 9216;     // 2048
    float* sWvs = smem + 11264;    // 1024
    float* nsT  = smem + 12288;    // 64*34
    float* nvT  = smem + 14464;    // 96*34
    int tid = threadIdx.x;
    int base = blockIdx.x * 32;

    for (int i = tid; i < 6144; i += 256) sWss[i] = Wss[i];
    for (int i = tid; i < 3072; i += 256) sWvv[i] = Wvv[i];
    for (int i = tid; i < 2048; i += 256) sWsv[i] = Wsv[i];
    for (int i = tid; i < 1024; i += 256) sWvs[i] = Wvs[i];
    for (int i = tid; i < 2048; i += 256) {
        int m = i >> 6, u = i & 63;
        int n = base + m;
        nsT[u * 34 + m] = (n < N) ? ns[(size_t)n * 64 + u] : 0.f;
    }
    for (int i = tid; i < 3072; i += 256) {
        int m = i / 96, f = i % 96;
        int u = f / 3, c = f % 3;
        int n = base + m;
        nvT[(c * 32 + u) * 34 + m] = (n < N) ? nv[(size_t)n * 96 + f] : 0.f;
    }
    __syncthreads();

    int tx = tid & 15, ty = tid >> 4;
    int m2 = tx * 2;
    int e6 = ty * 6, e2 = ty * 2;

    float pP[2][6] = {};
    float pQ[2][6][3] = {};
    float pS[2][2] = {};
    float pV[2][2][3] = {};

    for (int u = 0; u < 64; ++u) {
        float2 x = *(const float2*)&nsT[u * 34 + m2];
        float w6[6];
        *(float2*)&w6[0] = *(const float2*)&sWss[u * 96 + e6 + 0];
        *(float2*)&w6[2] = *(const float2*)&sWss[u * 96 + e6 + 2];
        *(float2*)&w6[4] = *(const float2*)&sWss[u * 96 + e6 + 4];
        float2 w2 = *(const float2*)&sWsv[u * 32 + e2];
#pragma unroll
        for (int j = 0; j < 6; ++j) { pP[0][j] += x.x * w6[j]; pP[1][j] += x.y * w6[j]; }
        pS[0][0] += x.x * w2.x; pS[0][1] += x.x * w2.y;
        pS[1][0] += x.y * w2.x; pS[1][1] += x.y * w2.y;
    }
    for (int u = 0; u < 32; ++u) {
        float2 x0 = *(const float2*)&nvT[(0 * 32 + u) * 34 + m2];
        float2 x1 = *(const float2*)&nvT[(1 * 32 + u) * 34 + m2];
        float2 x2 = *(const float2*)&nvT[(2 * 32 + u) * 34 + m2];
        float w6[6];
        *(float2*)&w6[0] = *(const float2*)&sWvv[u * 96 + e6 + 0];
        *(float2*)&w6[2] = *(const float2*)&sWvv[u * 96 + e6 + 2];
        *(float2*)&w6[4] = *(const float2*)&sWvv[u * 96 + e6 + 4];
        float2 w2 = *(const float2*)&sWvs[u * 32 + e2];
#pragma unroll
        for (int j = 0; j < 6; ++j) {
            pQ[0][j][0] += x0.x * w6[j]; pQ[1][j][0] += x0.y * w6[j];
            pQ[0][j][1] += x1.x * w6[j]; pQ[1][j][1] += x1.y * w6[j];
            pQ[0][j][2] += x2.x * w6[j]; pQ[1][j][2] += x2.y * w6[j];
        }
        pV[0][0][0] += x0.x * w2.x; pV[0][1][0] += x0.x * w2.y;
        pV[1][0][0] += x0.y * w2.x; pV[1][1][0] += x0.y * w2.y;
        pV[0][0][1] += x1.x * w2.x; pV[0][1][1] += x1.x * w2.y;
        pV[1][0][1] += x1.y * w2.x; pV[1][1][1] += x1.y * w2.y;
        pV[0][0][2] += x2.x * w2.x; pV[0][1][2] += x2.x * w2.y;
        pV[1][0][2] += x2.y * w2.x; pV[1][1][2] += x2.y * w2.y;
    }

    __syncthreads();
    unsigned short* PT = (unsigned short*)smem;   // [32][512] ushort
#pragma unroll
    for (int m = 0; m < 2; ++m) {
        int nr = m2 + m;
#pragma unroll
        for (int j = 0; j < 6; ++j) {
            int e = e6 + j;
            unsigned int lo = pack2(C_TP1_SS * pP[m][j], C_TP1_VV * pQ[m][j][0]);
            unsigned int hi = pack2(C_TP1_VV * pQ[m][j][1], C_TP1_VV * pQ[m][j][2]);
            *(uint2*)&PT[nr * 512 + e * 4] = make_uint2(lo, hi);
        }
#pragma unroll
        for (int j = 0; j < 2; ++j) {
            int w = e2 + j;
            unsigned int lo = pack2(C_TP1_SV * pS[m][j], C_TP1_VS * pV[m][j][0]);
            unsigned int hi = pack2(C_TP1_VS * pV[m][j][1], C_TP1_VS * pV[m][j][2]);
            *(uint2*)&PT[nr * 512 + (96 + w) * 4] = make_uint2(lo, hi);
        }
    }
    __syncthreads();
    for (int i = tid; i < 2048; i += 256) {
        int n = base + (i >> 6);
        if (n < N) ((int4*)PREb)[(size_t)base * 64 + i] = ((const int4*)PT)[i];
    }
}

// ============ CSR build: histogram -> scan -> scatter (VERIFIED) ============
__global__ void k_hist(const int* __restrict__ erow, int* __restrict__ CNT, int E)
{
    int e = blockIdx.x * 256 + threadIdx.x;
    if (e < E) atomicAdd(&CNT[erow[e]], 1);
}

__global__ void k_scan(const int* __restrict__ CNT, int* __restrict__ OFFS, int N, int E)
{
    __shared__ int part[1024];
    int t = threadIdx.x;
    int chunk = (N + 1023) >> 10;
    int b0 = t * chunk; if (b0 > N) b0 = N;
    int b1 = b0 + chunk; if (b1 > N) b1 = N;
    int s = 0;
    for (int i = b0; i < b1; ++i) s += CNT[i];
    part[t] = s;
    __syncthreads();
    for (int off = 1; off < 1024; off <<= 1) {
        int v = (t >= off) ? part[t - off] : 0;
        __syncthreads();
        part[t] += v;
        __syncthreads();
    }
    int run = part[t] - s;
    for (int i = b0; i < b1; ++i) { OFFS[i] = run; run += CNT[i]; }
    if (t == 1023) OFFS[N] = E;
}

__global__ void k_scatter(const int* __restrict__ erow, const int* __restrict__ ecol,
                          const float4* __restrict__ esh, const int* __restrict__ OFFS,
                          int* __restrict__ CUR, int* __restrict__ EJ,
                          float4* __restrict__ ESHS, int E)
{
    int e = blockIdx.x * 256 + threadIdx.x;
    if (e >= E) return;
    int r = erow[e];
    int p = OFFS[r] + atomicAdd(&CUR[r], 1);
    EJ[p] = ecol[e];
    ESHS[p] = esh[e];
}

// ============ K_agg v2: depth-2 software pipeline over the edge list (VERIFIED r17) ============
__global__ void k_agg(const unsigned short* __restrict__ PREb, const int* __restrict__ EJ,
                      const float4* __restrict__ ESHS, const int* __restrict__ OFFS,
                      float* __restrict__ AGG, int N)
{
    int wv = blockIdx.x * 4 + (threadIdx.x >> 6);
    if (wv >= N) return;
    int lane = threadIdx.x & 63;
    int beg = OFFS[wv], end = OFFS[wv + 1];
    const int4* pb = (const int4*)PREb;
    float a0 = 0.f, a1 = 0.f;
    float b00 = 0.f, b01 = 0.f, b02 = 0.f, b10 = 0.f, b11 = 0.f, b12 = 0.f;
    int gsrc = (lane >= 48) ? (lane - 16) : lane;

    int   j1 = 0;
    float4 sh0 = make_float4(0.f, 0.f, 0.f, 0.f), sh1 = sh0;
    int4  g0 = make_int4(0, 0, 0, 0);
    if (beg < end) {
        int j0 = EJ[beg];
        sh0 = ESHS[beg];
        g0 = pb[(size_t)j0 * 64 + lane];
    }
    if (beg + 1 < end) {
        j1 = EJ[beg + 1];
        sh1 = ESHS[beg + 1];
    }
    for (int i = beg; i < end; ++i) {
        float4 sh = sh0;
        int4 g = g0;
        if (i + 1 < end) {
            g0 = pb[(size_t)j1 * 64 + lane];
            sh0 = sh1;
            if (i + 2 < end) {
                j1 = EJ[i + 2];
                sh1 = ESHS[i + 2];
            }
        }
        unsigned int gx = (unsigned int)g.x, gy = (unsigned int)g.y;
        unsigned int gz = (unsigned int)g.z, gw = (unsigned int)g.w;
        float P0 = blo(gx), Q00 = bhi(gx), Q01 = blo(gy), Q02 = bhi(gy);
        float P1 = blo(gz), Q10 = bhi(gz), Q11 = blo(gw), Q12 = bhi(gw);
        float ms0 = sh.x * P0 + sh.y * Q00 + sh.z * Q01 + sh.w * Q02;
        float ms1 = sh.x * P1 + sh.y * Q10 + sh.z * Q11 + sh.w * Q12;
        float sg0 = sigmoidf_(ms0);
        float sg1 = sigmoidf_(ms1);
        float sw0 = __shfl(sg0, gsrc);
        float sw1 = __shfl(sg1, gsrc);
        if (lane < 32) {
            a0 += ms0 * sg0;
            a1 += ms1 * sg1;
        } else if (lane >= 48) {
            b00 += (sh.y * P0 + sh.x * Q00) * sw0;
            b01 += (sh.z * P0 + sh.x * Q01) * sw0;
            b02 += (sh.w * P0 + sh.x * Q02) * sw0;
            b10 += (sh.y * P1 + sh.x * Q10) * sw1;
            b11 += (sh.z * P1 + sh.x * Q11) * sw1;
            b12 += (sh.w * P1 + sh.x * Q12) * sw1;
        }
    }
    float* ab = AGG + (size_t)wv * 160;
    if (lane < 32) {
        *(float2*)&ab[2 * lane] = make_float2(a0, a1);
    } else if (lane >= 48) {
        int o = 64 + 6 * (lane - 48);
        *(float2*)&ab[o + 0] = make_float2(b00, b01);
        *(float2*)&ab[o + 2] = make_float2(b02, b10);
        *(float2*)&ab[o + 4] = make_float2(b11, b12);
    }
}

// ============ K_lin1: apply lin1 to aggregates, in place (VERIFIED) ============
__global__ void k_lin1(float* __restrict__ AGG, const float* __restrict__ L1s,
                       const float* __restrict__ L1v, int N)
{
    __shared__ float sLs[64 * 64];
    __shared__ float sLv[32 * 32];
    __shared__ float sS[4][64];
    __shared__ float sV[4][96];
    int tid = threadIdx.x;
    for (int i = tid; i < 64 * 64; i += 256) sLs[i] = L1s[i];
    for (int i = tid; i < 32 * 32; i += 256) sLv[i] = L1v[i];
    __syncthreads();
    int wid = tid >> 6, lane = tid & 63;
    int gw = blockIdx.x * 4 + wid, nw = gridDim.x * 4;
    for (int n = gw; n < N; n += nw) {
        float* base = AGG + (size_t)n * 160;
        sS[wid][lane] = base[lane];
        sV[wid][lane] = base[64 + lane];
        if (lane < 32) sV[wid][64 + lane] = base[128 + lane];
        float acc = 0.f;
        for (int u = 0; u < 64; ++u) acc += sS[wid][u] * sLs[u * 64 + lane];
        float o0 = 0.f, o1 = 0.f, o2 = 0.f;
        if (lane < 32) {
            for (int u = 0; u < 32; ++u) {
                float wv = sLv[u * 32 + lane];
                o0 += sV[wid][u * 3 + 0] * wv;
                o1 += sV[wid][u * 3 + 1] * wv;
                o2 += sV[wid][u * 3 + 2] * wv;
            }
        }
        base[lane] = C_LIN_S * acc;
        if (lane < 32) {
            base[64 + lane * 3 + 0] = C_LIN_V * o0;
            base[64 + lane * 3 + 1] = C_LIN_V * o1;
            base[64 + lane * 3 + 2] = C_LIN_V * o2;
        }
    }
}

// ============ K_wprep v4: ALL regions in swizzled per-lane fragment order (VERIFIED r14) ============
__global__ void k_wprep(const float* __restrict__ W2ss, const float* __restrict__ W2vv,
                        const float* __restrict__ W2sv, const float* __restrict__ W2vs,
                        unsigned short* __restrict__ WT)
{
    int i = blockIdx.x * 256 + threadIdx.x;
    if (i >= 819200) return;
    float val;
    if (i < 393216) {
        int nt = i / 131072;
        int r  = i % 131072;
        int kb = r >> 9;
        int q  = r & 511;
        int lane = q >> 3, j = q & 7;
        int w = nt * 32 + (lane & 31);
        int k = kb * 16 + (lane >> 5) * 8 + j;
        val = W2ss[(size_t)k * 96 + w] * C_TP2_SS;
    } else if (i < 688128) {
        int ii = i - 393216;
        int nt = ii / 98304;
        int r  = ii % 98304;
        int kb = r >> 9;
        int q  = r & 511;
        int lane = q >> 3, j = q & 7;
        int w = nt * 32 + (lane & 31);
        int k = kb * 16 + (lane >> 5) * 8 + j;
        int q2 = k & 1023;
        val = W2vv[(size_t)q2 * 96 + w] * C_TP2_VV;
    } else if (i < 753664) {
        int ii = i - 688128;
        int kb = ii >> 9;
        int q  = ii & 511;
        int lane = q >> 3, j = q & 7;
        int w = lane & 31;
        int k = kb * 16 + (lane >> 5) * 8 + j;
        val = W2sv[(size_t)k * 32 + w] * C_TP2_SVVS;
    } else {
        int ii = i - 753664;
        int kb = ii >> 9;
        int q  = ii & 511;
        int lane = q >> 3, j = q & 7;
        int w = lane & 31;
        int k = kb * 16 + (lane >> 5) * 8 + j;
        val = W2vs[(size_t)k * 32 + w] * C_TP2_SVVS;
    }
    WT[i] = f2bf(val);
}

// ============ K4ab_mfma v11 (VERIFIED r16/r17): bf16 staging, swizzled B, launch_bounds(256,4) ============
#define OFF_NS 0
#define OFF_AS 2176
#define OFF_NV 4352
#define OFF_AV 7552
__global__ __launch_bounds__(256, 4) void k4ab_mfma(const float* __restrict__ ns, const float* __restrict__ nv,
                                                    const float* __restrict__ AGG,
                                                    const unsigned short* __restrict__ WT,
                                                    float* __restrict__ SOUT, float* __restrict__ VOUT, int N)
{
    __shared__ float smem[6144];            // 24.6 KB: staging (bf16 overlay) then epilogue
    unsigned short* stg = (unsigned short*)smem;
    const unsigned short* Wt_ss = WT;
    const unsigned short* Wt_vv = WT + 393216;
    const unsigned short* Wt_sv = WT + 688128;
    const unsigned short* Wt_vs = WT + 753664;

    int tid = threadIdx.x;
    int base = blockIdx.x * 32;

    for (int i = tid; i < 2048; i += 256) {
        int mm = i >> 6, u = i & 63;
        int n = base + mm;
        stg[OFF_NS + mm * 68 + u] = f2bf((n < N) ? ns[(size_t)n * 64 + u] : 0.f);
        stg[OFF_AS + mm * 68 + u] = f2bf((n < N) ? AGG[(size_t)n * 160 + u] : 0.f);
    }
    for (int i = tid; i < 3072; i += 256) {
        int mm = i / 96, r = i % 96;
        int c = r >> 5, q = r & 31;
        int n = base + mm;
        stg[OFF_NV + mm * 100 + r] = f2bf((n < N) ? nv[(size_t)n * 96 + q * 3 + c] : 0.f);
        stg[OFF_AV + mm * 100 + r] = f2bf((n < N) ? AGG[(size_t)n * 160 + 64 + q * 3 + c] : 0.f);
    }
    __syncthreads();

    int wid = tid >> 6;
    int l = tid & 63;
    int m = l & 31;
    int half = l >> 5;
    const unsigned short* pns = stg + OFF_NS + m * 68;
    const unsigned short* pas = stg + OFF_AS + m * 68;
    const unsigned short* pnv = stg + OFF_NV + m * 100;
    const unsigned short* pav = stg + OFF_AV + m * 100;

    f32x16 accA[3];
    f32x16 accP[3];
#pragma unroll
    for (int a = 0; a < 3; ++a) {
#pragma unroll
        for (int r = 0; r < 16; ++r) { accA[a][r] = 0.f; accP[a][r] = 0.f; }
    }

    if (wid == 0) {
        float4 ys[4][2];
#pragma unroll
        for (int t = 0; t < 4; ++t) {
            ys[t][0] = ld4bf(&pas[t * 16 + half * 8]);
            ys[t][1] = ld4bf(&pas[t * 16 + half * 8 + 4]);
        }
        const int4* wb = (const int4*)Wt_ss + l;
        for (int u0 = 0; u0 < 64; u0 += 4) {
            float4 x4 = ld4bf(&pns[u0]);
#pragma unroll
            for (int uu = 0; uu < 4; ++uu) {
                float x = (uu == 0) ? x4.x : (uu == 1) ? x4.y : (uu == 2) ? x4.z : x4.w;
                const int4* wu = wb + (u0 + uu) * 256;
                int4 b[4];
#pragma unroll
                for (int t = 0; t < 4; ++t) b[t] = wu[t * 64];
                short8 af[4];
#pragma unroll
                for (int t = 0; t < 4; ++t)
                    af[t] = pack8(x * ys[t][0].x, x * ys[t][0].y, x * ys[t][0].z, x * ys[t][0].w,
                                  x * ys[t][1].x, x * ys[t][1].y, x * ys[t][1].z, x * ys[t][1].w);
#pragma unroll
                for (int nt = 0; nt < 3; ++nt) {
                    int4 nb[4];
                    if (nt < 2) {
#pragma unroll
                        for (int t = 0; t < 4; ++t) nb[t] = wu[(nt + 1) * 16384 + t * 64];
                    }
#pragma unroll
                    for (int t = 0; t < 4; ++t)
                        accA[nt] = __builtin_amdgcn_mfma_f32_32x32x16_bf16(af[t], as_s8(b[t]), accA[nt], 0, 0, 0);
                    if (nt < 2) {
#pragma unroll
                        for (int t = 0; t < 4; ++t) b[t] = nb[t];
                    }
                }
            }
        }
    } else if (wid == 1) {
        float4 yv[3][2][2];
#pragma unroll
        for (int c = 0; c < 3; ++c)
#pragma unroll
            for (int t = 0; t < 2; ++t) {
                yv[c][t][0] = ld4bf(&pav[c * 32 + t * 16 + half * 8]);
                yv[c][t][1] = ld4bf(&pav[c * 32 + t * 16 + half * 8 + 4]);
            }
        const int4* wb = (const int4*)Wt_vv + l;
#pragma unroll
        for (int c = 0; c < 3; ++c) {
            for (int u0 = 0; u0 < 32; u0 += 4) {
                float4 x4 = ld4bf(&pnv[c * 32 + u0]);
#pragma unroll
                for (int uu = 0; uu < 4; ++uu) {
                    float x = (uu == 0) ? x4.x : (uu == 1) ? x4.y : (uu == 2) ? x4.z : x4.w;
                    const int4* wu = wb + c * 4096 + (u0 + uu) * 128;
                    int4 b[2];
                    b[0] = wu[0];
                    b[1] = wu[64];
                    short8 af[2];
#pragma unroll
                    for (int t = 0; t < 2; ++t)
                        af[t] = pack8(x * yv[c][t][0].x, x * yv[c][t][0].y, x * yv[c][t][0].z, x * yv[c][t][0].w,
                                      x * yv[c][t][1].x, x * yv[c][t][1].y, x * yv[c][t][1].z, x * yv[c][t][1].w);
#pragma unroll
                    for (int nt = 0; nt < 3; ++nt) {
                        int4 nb[2];
                        if (nt < 2) {
                            nb[0] = wu[(nt + 1) * 12288];
                            nb[1] = wu[(nt + 1) * 12288 + 64];
                        }
                        accA[nt] = __builtin_amdgcn_mfma_f32_32x32x16_bf16(af[0], as_s8(b[0]), accA[nt], 0, 0, 0);
                        accA[nt] = __builtin_amdgcn_mfma_f32_32x32x16_bf16(af[1], as_s8(b[1]), accA[nt], 0, 0, 0);
                        if (nt < 2) { b[0] = nb[0]; b[1] = nb[1]; }
                    }
                }
            }
        }
    } else if (wid == 2) {
        float4 yv[3][2][2];
#pragma unroll
        for (int c = 0; c < 3; ++c)
#pragma unroll
            for (int t = 0; t < 2; ++t) {
                yv[c][t][0] = ld4bf(&pav[c * 32 + t * 16 + half * 8]);
                yv[c][t][1] = ld4bf(&pav[c * 32 + t * 16 + half * 8 + 4]);
            }
        const int4* bp = (const int4*)Wt_sv + l;
#pragma unroll
        for (int c = 0; c < 3; ++c) {
            f32x16 acc;
#pragma unroll
            for (int r = 0; r < 16; ++r) acc[r] = 0.f;
            int4 b0 = bp[0], b1 = bp[64];
            int4 n0 = bp[128], n1 = bp[192];
            for (int u = 0; u < 64; ++u) {
                int up = (u + 2 < 64) ? (u + 2) : 63;
                const int4* bq = bp + up * 128;
                int4 p0 = bq[0], p1 = bq[64];
                float x = ldbf(&pns[u]);
#pragma unroll
                for (int t = 0; t < 2; ++t) {
                    short8 af = pack8(x * yv[c][t][0].x, x * yv[c][t][0].y, x * yv[c][t][0].z, x * yv[c][t][0].w,
                                      x * yv[c][t][1].x, x * yv[c][t][1].y, x * yv[c][t][1].z, x * yv[c][t][1].w);
                    int4 braw = (t == 0) ? b0 : b1;
                    acc = __builtin_amdgcn_mfma_f32_32x32x16_bf16(af, as_s8(braw), acc, 0, 0, 0);
                }
                b0 = n0; b1 = n1;
                n0 = p0; n1 = p1;
            }
            accP[c] = acc;
        }
    } else {
        float4 ys[4][2];
#pragma unroll
        for (int t = 0; t < 4; ++t) {
            ys[t][0] = ld4bf(&pas[t * 16 + half * 8]);
            ys[t][1] = ld4bf(&pas[t * 16 + half * 8 + 4]);
        }
        const int4* bp = (const int4*)Wt_vs + l;
#pragma unroll
        for (int c = 0; c < 3; ++c) {
            f32x16 acc;
#pragma unroll
            for (int r = 0; r < 16; ++r) acc[r] = 0.f;
            int4 b0 = bp[0], b1 = bp[64], b2 = bp[128], b3 = bp[192];
            int4 n0 = bp[256], n1 = bp[320], n2 = bp[384], n3 = bp[448];
            for (int u = 0; u < 32; ++u) {
                int up = (u + 2 < 32) ? (u + 2) : 31;
                const int4* bq = bp + up * 256;
                int4 p0 = bq[0], p1 = bq[64], p2 = bq[128], p3 = bq[192];
                float x = ldbf(&pnv[c * 32 + u]);
#pragma unroll
                for (int t = 0; t < 4; ++t) {
                    short8 af = pack8(x * ys[t][0].x, x * ys[t][0].y, x * ys[t][0].z, x * ys[t][0].w,
                                      x * ys[t][1].x, x * ys[t][1].y, x * ys[t][1].z, x * ys[t][1].w);
                    int4 braw = (t == 0) ? b0 : (t == 1) ? b1 : (t == 2) ? b2 : b3;
                    acc = __builtin_amdgcn_mfma_f32_32x32x16_bf16(af, as_s8(braw), acc, 0, 0, 0);
                }
                b0 = n0; b1 = n1; b2 = n2; b3 = n3;
                n0 = p0; n1 = p1; n2 = p2; n3 = p3;
            }
            accP[c] = acc;
        }
    }

    __syncthreads();
    if (wid == 0) {
#pragma unroll
        for (int nt = 0; nt < 3; ++nt)
#pragma unroll
            for (int r = 0; r < 16; ++r) {
                int row = (r & 3) + 8 * (r >> 2) + 4 * half;
                smem[row * 96 + nt * 32 + m] = accA[nt][r];
            }
    }
    if (wid == 2) {
#pragma unroll
        for (int c = 0; c < 3; ++c)
#pragma unroll
            for (int r = 0; r < 16; ++r) {
                int row = (r & 3) + 8 * (r >> 2) + 4 * half;
                smem[3072 + row * 96 + m * 3 + c] = accP[c][r];
            }
    }
    __syncthreads();
    if (wid == 1) {
#pragma unroll
        for (int nt = 0; nt < 3; ++nt)
#pragma unroll
            for (int r = 0; r < 16; ++r) {
                int row = (r & 3) + 8 * (r >> 2) + 4 * half;
                smem[row * 96 + nt * 32 + m] += accA[nt][r];
            }
    }
    if (wid == 3) {
#pragma unroll
        for (int c = 0; c < 3; ++c)
#pragma unroll
            for (int r = 0; r < 16; ++r) {
                int row = (r & 3) + 8 * (r >> 2) + 4 * half;
                smem[3072 + row * 96 + m * 3 + c] += accP[c][r];
            }
    }
    __syncthreads();
    for (int i = tid; i < 3072; i += 256) {
        int n = base + i / 96;
        if (n < N) SOUT[(size_t)n * 96 + i % 96] = smem[i];
    }
    for (int i = tid; i < 3072; i += 256) {
        int n = base + i / 96;
        if (n < N) VOUT[(size_t)n * 96 + i % 96] = smem[3072 + i];
    }
}

// ============ K5: gate + lin2 + residual (VERIFIED) ============
__global__ void k5(const float* __restrict__ SOUT, const float* __restrict__ VOUT,
                   const float* __restrict__ ns, const float* __restrict__ nv,
                   const float* __restrict__ L2s, const float* __restrict__ L2v,
                   float* __restrict__ out, int N)
{
    __shared__ float sLs[64 * 64];
    __shared__ float sLv[32 * 32];
    __shared__ float sGS[4][64];
    __shared__ float sGV[4][96];
    int tid = threadIdx.x;
    for (int i = tid; i < 64 * 64; i += 256) sLs[i] = L2s[i];
    for (int i = tid; i < 32 * 32; i += 256) sLv[i] = L2v[i];
    __syncthreads();
    int wid = tid >> 6, lane = tid & 63;
    int gw = blockIdx.x * 4 + wid, nw = gridDim.x * 4;
    for (int n = gw; n < N; n += nw) {
        float so = SOUT[(size_t)n * 96 + lane];
        float sig = 0.f;
        if (lane < 32) sig = sigmoidf_(SOUT[(size_t)n * 96 + 64 + lane]);
        float sigA = __shfl(sig, lane / 3);
        float sigB = __shfl(sig, (64 + lane) / 3);
        sGS[wid][lane] = so * sigmoidf_(so);
        float v0 = VOUT[(size_t)n * 96 + lane];
        sGV[wid][lane] = v0 * sigA;
        if (lane < 32) {
            float v1 = VOUT[(size_t)n * 96 + 64 + lane];
            sGV[wid][64 + lane] = v1 * sigB;
        }
        float acc = 0.f;
        for (int u = 0; u < 64; ++u) acc += sGS[wid][u] * sLs[u * 64 + lane];
        out[(size_t)n * 64 + lane] = ns[(size_t)n * 64 + lane] + C_LIN_S * acc;
        if (lane < 32) {
            float a0 = 0.f, a1 = 0.f, a2 = 0.f;
            for (int u = 0; u < 32; ++u) {
                float wv = sLv[u * 32 + lane];
                a0 += sGV[wid][u * 3 + 0] * wv;
                a1 += sGV[wid][u * 3 + 1] * wv;
                a2 += sGV[wid][u * 3 + 2] * wv;
            }
            size_t ob = (size_t)N * 64 + (size_t)n * 96 + lane * 3;
            out[ob + 0] = nv[(size_t)n * 96 + lane * 3 + 0] + C_LIN_V * a0;
            out[ob + 1] = nv[(size_t)n * 96 + lane * 3 + 1] + C_LIN_V * a1;
            out[ob + 2] = nv[(size_t)n * 96 + lane * 3 + 2] + C_LIN_V * a2;
        }
    }
}

extern "C" void kernel_launch(void* const* d_in, const int* in_sizes, int n_in,
                              void* d_out, int out_size, void* d_ws, size_t ws_size,
                              hipStream_t stream)
{
    const float* node_s = (const float*)d_in[0];
    const float* node_v = (const float*)d_in[1];
    const float4* esh   = (const float4*)d_in[2];
    const int* erow     = (const int*)d_in[4];
    const int* ecol     = (const int*)d_in[5];
    const float* W1ss   = (const float*)d_in[6];
    const float* W1vv   = (const float*)d_in[7];
    const float* W1sv   = (const float*)d_in[8];
    const float* W1vs   = (const float*)d_in[9];
    const float* L1s    = (const float*)d_in[10];
    const float* L1v    = (const float*)d_in[11];
    const float* W2ss   = (const float*)d_in[12];
    const float* W2vv   = (const float*)d_in[13];
    const float* W2sv   = (const float*)d_in[14];
    const float* W2vs   = (const float*)d_in[15];
    const float* L2s    = (const float*)d_in[16];
    const float* L2v    = (const float*)d_in[17];
    int N = in_sizes[0] / 64;
    int E = in_sizes[4];

    char* ws = (char*)d_ws;
    float* AGG            = (float*)ws;                                   // N*160 f32
    unsigned short* PREb  = (unsigned short*)(ws + (size_t)N * 640);      // N*512 bf16
    float* SOUT           = (float*)(ws + (size_t)N * 640);               // aliases PREb (dead then)
    float* VOUT           = (float*)(ws + (size_t)N * 640 + (size_t)N * 384);
    unsigned short* WT    = (unsigned short*)(ws + (size_t)N * 1664);     // 819200 bf16
    int* EJ               = (int*)(ws + (size_t)N * 1664 + 1638400);      // E int
    float4* ESHS          = (float4*)((char*)EJ + (size_t)E * 4);         // E float4
    int* CNT              = (int*)((char*)ESHS + (size_t)E * 16);         // N int
    int* OFFS             = CNT + N;                                      // N+16 int
    int* CUR              = OFFS + N + 16;                                // N int

    hipMemsetAsync(CNT, 0, (size_t)(3 * N + 16) * 4, stream);
    k_pre<<<(N + 31) / 32, 256, 0, stream>>>(node_s, node_v, W1ss, W1vv, W1sv, W1vs, PREb, N);
    k_hist<<<(E + 255) / 256, 256, 0, stream>>>(erow, CNT, E);
    k_scan<<<1, 1024, 0, stream>>>(CNT, OFFS, N, E);
    k_scatter<<<(E + 255) / 256, 256, 0, stream>>>(erow, ecol, esh, OFFS, CUR, EJ, ESHS, E);
    k_agg<<<(N + 3) / 4, 256, 0, stream>>>(PREb, EJ, ESHS, OFFS, AGG, N);
    k_lin1<<<1024, 256, 0, stream>>>(AGG, L1s, L1v, N);
    k_wprep<<<3200, 256, 0, stream>>>(W2ss, W2vv, W2sv, W2vs, WT);
    k4ab_mfma<<<(N + 31) / 32, 256, 0, stream>>>(node_s, node_v, AGG, WT, SOUT, VOUT, N);
    k5<<<1024, 256, 0, stream>>>(SOUT, VOUT, node_s, node_v, L2s, L2v, (float*)d_out, N);
}